// Round 2
// baseline (1893.515 us; speedup 1.0000x reference)
//
#include <hip/hip_runtime.h>
#include <hip/hip_bf16.h>
#include <math.h>

#define NB 4
#define B  2048
#define L  168
#define DI 9
#define H  96
#define N2 48

#define CH   24    // h-chunk per LDS pass
#define NCH  4     // 96/24
#define LSTR 180   // ut row stride (8-float zero front pad + 168 + 4; 180%32=20 -> odd*4)
#define ZSTR 172   // z2t row stride (172%32=12 -> odd*4)
#define PSTR 177   // psum/psq row stride (odd)

__device__ __forceinline__ float gelu_f(float x) {
    float x3 = x * x * x;
    float y  = 0.7978845608028654f * (x + 0.044715f * x3);
    float ey = __expf(2.0f * y);
    float t  = 1.0f - 2.0f / (ey + 1.0f);
    return 0.5f * x * (1.0f + t);
}

// ---------------- S4D kernel generation: K[i][h][l] ----------------
__global__ void kgen_kernel(const float* __restrict__ log_dt, const float* __restrict__ lar,
                            const float* __restrict__ aim, const float* __restrict__ cre,
                            const float* __restrict__ cim, float* __restrict__ K)
{
    const int ih   = blockIdx.x;      // i*96+h, 384 blocks
    const int lane = threadIdx.x;     // 64
    float ctre = 0.f, ctim = 0.f, pre = 0.f, pim = 0.f, mre = 0.f, mim = 0.f;
    if (lane < N2) {
        float dt  = expf(log_dt[ih]);
        int   idx = ih * N2 + lane;
        float reA = -expf(lar[idx]);
        float imA = aim[idx];
        float dre = dt * reA, dim = dt * imA;
        float er  = expf(dre);
        float sv, cv;
        sincosf(dim, &sv, &cv);
        mre = er * cv; mim = er * sv;              // exp(dtA)
        float nre = mre - 1.0f, nim = mim;         // exp(dtA)-1
        float den = reA * reA + imA * imA;
        float tre = (nre * reA + nim * imA) / den; // (exp(dtA)-1)/A
        float tim = (nim * reA - nre * imA) / den;
        float cr = cre[idx], ci = cim[idx];
        ctre = cr * tre - ci * tim;                // Ct
        ctim = cr * tim + ci * tre;
        pre = 1.0f; pim = 0.0f;                    // exp(dtA*0)
    }
    float* Kr = K + ih * L;
    for (int l = 0; l < L; ++l) {
        float term = ctre * pre - ctim * pim;      // Re(Ct * p)
        #pragma unroll
        for (int off = 32; off > 0; off >>= 1) term += __shfl_xor(term, off, 64);
        if (lane == 0) Kr[l] = 2.0f * term;
        float nr = pre * mre - pim * mim;
        float ni = pre * mim + pim * mre;
        pre = nr; pim = ni;
    }
}

// ---------------- encoder: h[b,l,:] = x[b,l,:] @ enc_W + enc_b ----------------
__launch_bounds__(256)
__global__ void enc_kernel(const float* __restrict__ x, const float* __restrict__ W,
                           const float* __restrict__ bias, float* __restrict__ h)
{
    __shared__ float Ws[DI * H];
    __shared__ float bs[H];
    const int tid = threadIdx.x;
    for (int e = tid; e < DI * H; e += 256) Ws[e] = W[e];
    if (tid < H) bs[tid] = bias[tid];
    __syncthreads();
    const int total = B * L * H;
    for (int idx = blockIdx.x * 256 + tid; idx < total; idx += 2048 * 256) {
        int r = idx / H, c = idx - r * H;
        const float* xr = x + r * DI;
        float a = bs[c];
        #pragma unroll
        for (int k = 0; k < DI; ++k) a = fmaf(xr[k], Ws[k * H + c], a);
        h[idx] = a;
    }
}

// ---------------- fused S4 block: conv+skip -> gelu -> @W_out+b -> residual LN, in-place ----------------
// h-chunks of 24 -> LDS 36.8 KB -> 4 blocks/CU by LDS; VGPR capped for >=6 waves/SIMD.
__launch_bounds__(512, 6)
__global__ void s4_block(float* __restrict__ hbuf, const float* __restrict__ Kg,
                         const float* __restrict__ Wg, const float* __restrict__ bout,
                         const float* __restrict__ Dsk, const float* __restrict__ lnw,
                         const float* __restrict__ lnb)
{
    __shared__ float smem[9200];
    float* ut   = smem;                   // [24][LSTR] u chunk, transposed, front-padded
    float* z2t  = smem + CH * LSTR;       // [24][ZSTR] gelu output chunk, transposed
    float* psum = smem;                   // overlay after all matmul reads: [24][PSTR]
    float* psq  = smem + CH * PSTR;       // [24][PSTR]
    float* muA  = smem + 8848;
    float* rsA  = smem + 9024;

    const int tid = threadIdx.x;
    const int b   = blockIdx.x;
    float* __restrict__ hb = hbuf + (size_t)b * (L * H);

    // zero front pads once
    for (int e = tid; e < CH * 8; e += 512) ut[(e >> 3) * LSTR + (e & 7)] = 0.0f;

    const bool act = tid < 504;
    const int  mlt = tid / CH;            // 0..20 (l-tile), also conv lt
    const int  mhc = tid - mlt * CH;      // 0..23 (h-local)
    const int  ml0 = mlt * 8;
    float acc2[8][4];
    #pragma unroll
    for (int i = 0; i < 8; ++i) { acc2[i][0] = acc2[i][1] = acc2[i][2] = acc2[i][3] = 0.f; }

    for (int ch = 0; ch < NCH; ++ch) {
        __syncthreads();
        // stage u chunk (transposed): ut[kl][8+l] = u[l][ch*24+kl]
        for (int e = tid; e < CH * L; e += 512) {
            int l = e / CH, kl = e - l * CH;
            ut[kl * LSTR + 8 + l] = hb[l * H + ch * CH + kl];
        }
        __syncthreads();
        // conv + skip + gelu: 504 tasks = 21 l-tiles x 24 h_local, one pass
        if (act) {
            const int l0 = ml0;
            const int h  = ch * CH + mhc;
            const float* Krow = Kg + h * L;
            const float* urow = ut + mhc * LSTR;
            float acc[8] = {0, 0, 0, 0, 0, 0, 0, 0};
            for (int d0 = 0; d0 <= l0; d0 += 8) {
                const float* up = urow + (l0 - d0);
                float4 A0 = *(const float4*)(up);
                float4 A1 = *(const float4*)(up + 4);
                float4 A2 = *(const float4*)(up + 8);
                float4 A3 = *(const float4*)(up + 12);
                float uv[16] = {A0.x, A0.y, A0.z, A0.w, A1.x, A1.y, A1.z, A1.w,
                                A2.x, A2.y, A2.z, A2.w, A3.x, A3.y, A3.z, A3.w};
                float4 K0 = *(const float4*)(Krow + d0);
                float4 K1 = *(const float4*)(Krow + d0 + 4);
                float kv[8] = {K0.x, K0.y, K0.z, K0.w, K1.x, K1.y, K1.z, K1.w};
                #pragma unroll
                for (int dd = 0; dd < 8; ++dd) {
                    #pragma unroll
                    for (int i = 0; i < 8; ++i)
                        acc[i] = fmaf(kv[dd], uv[8 + i - dd], acc[i]);
                }
            }
            float  ds = Dsk[h];
            float4 U0 = *(const float4*)(urow + 8 + l0);
            float4 U1 = *(const float4*)(urow + 12 + l0);
            float uc[8] = {U0.x, U0.y, U0.z, U0.w, U1.x, U1.y, U1.z, U1.w};
            float zo[8];
            #pragma unroll
            for (int i = 0; i < 8; ++i) zo[i] = gelu_f(fmaf(ds, uc[i], acc[i]));
            float* zrow = z2t + mhc * ZSTR + l0;
            *(float4*)(zrow)     = make_float4(zo[0], zo[1], zo[2], zo[3]);
            *(float4*)(zrow + 4) = make_float4(zo[4], zo[5], zo[6], zo[7]);
        }
        __syncthreads();
        // partial matmul over this k-chunk: acc2 += z2t[k][l-tile] * W[k][h'-tile]
        if (act) {
            const float* Wc = Wg + ch * CH * H + mhc * 4;
            #pragma unroll 2
            for (int kl = 0; kl < CH; ++kl) {
                float4 w4 = *(const float4*)(Wc + kl * H);
                const float* zr = z2t + kl * ZSTR + ml0;
                float4 a0 = *(const float4*)(zr);
                float4 a1 = *(const float4*)(zr + 4);
                float av[8] = {a0.x, a0.y, a0.z, a0.w, a1.x, a1.y, a1.z, a1.w};
                #pragma unroll
                for (int i = 0; i < 8; ++i) {
                    acc2[i][0] = fmaf(av[i], w4.x, acc2[i][0]);
                    acc2[i][1] = fmaf(av[i], w4.y, acc2[i][1]);
                    acc2[i][2] = fmaf(av[i], w4.z, acc2[i][2]);
                    acc2[i][3] = fmaf(av[i], w4.w, acc2[i][3]);
                }
            }
        }
    }
    // bias + residual (global reads, before any write)
    if (act) {
        float4 bo = *(const float4*)(bout + mhc * 4);
        #pragma unroll
        for (int i = 0; i < 8; ++i) {
            float4 r = *(const float4*)(hb + (ml0 + i) * H + mhc * 4);
            acc2[i][0] += bo.x + r.x;
            acc2[i][1] += bo.y + r.y;
            acc2[i][2] += bo.z + r.z;
            acc2[i][3] += bo.w + r.w;
        }
    }
    __syncthreads();   // all LDS matmul reads done -> safe to overlay psum/psq
    if (act) {
        #pragma unroll
        for (int i = 0; i < 8; ++i) {
            float s = acc2[i][0] + acc2[i][1] + acc2[i][2] + acc2[i][3];
            float q = acc2[i][0] * acc2[i][0] + acc2[i][1] * acc2[i][1] +
                      acc2[i][2] * acc2[i][2] + acc2[i][3] * acc2[i][3];
            psum[mhc * PSTR + ml0 + i] = s;
            psq [mhc * PSTR + ml0 + i] = q;
        }
    }
    __syncthreads();
    if (tid < L) {
        float s = 0.f, q = 0.f;
        #pragma unroll 4
        for (int c = 0; c < CH; ++c) { s += psum[c * PSTR + tid]; q += psq[c * PSTR + tid]; }
        float m = s * (1.0f / 96.0f);
        float v = q * (1.0f / 96.0f) - m * m;
        muA[tid] = m;
        rsA[tid] = rsqrtf(v + 1e-5f);
    }
    __syncthreads();
    if (act) {
        float4 w4 = *(const float4*)(lnw + mhc * 4);
        float4 b4 = *(const float4*)(lnb + mhc * 4);
        #pragma unroll
        for (int i = 0; i < 8; ++i) {
            float m = muA[ml0 + i], r = rsA[ml0 + i];
            float4 o;
            o.x = fmaf((acc2[i][0] - m) * r, w4.x, b4.x);
            o.y = fmaf((acc2[i][1] - m) * r, w4.y, b4.y);
            o.z = fmaf((acc2[i][2] - m) * r, w4.z, b4.z);
            o.w = fmaf((acc2[i][3] - m) * r, w4.w, b4.w);
            *(float4*)(hb + (ml0 + i) * H + mhc * 4) = o;
        }
    }
}

// ---------------- decoder: h = h @ dec_W + dec_b, in-place per b ----------------
__launch_bounds__(512, 8)
__global__ void dec_kernel(float* __restrict__ hbuf, const float* __restrict__ Wg,
                           const float* __restrict__ bias)
{
    __shared__ float ht[CH * ZSTR];
    const int tid = threadIdx.x;
    const int b   = blockIdx.x;
    float* __restrict__ hb = hbuf + (size_t)b * (L * H);
    const bool act = tid < 504;
    const int  mlt = tid / CH, mhc = tid - mlt * CH;
    const int  ml0 = mlt * 8;
    float acc2[8][4];
    #pragma unroll
    for (int i = 0; i < 8; ++i) { acc2[i][0] = acc2[i][1] = acc2[i][2] = acc2[i][3] = 0.f; }

    for (int ch = 0; ch < NCH; ++ch) {
        __syncthreads();
        for (int e = tid; e < CH * L; e += 512) {
            int l = e / CH, kl = e - l * CH;
            ht[kl * ZSTR + l] = hb[l * H + ch * CH + kl];
        }
        __syncthreads();
        if (act) {
            const float* Wc = Wg + ch * CH * H + mhc * 4;
            #pragma unroll 2
            for (int kl = 0; kl < CH; ++kl) {
                float4 w4 = *(const float4*)(Wc + kl * H);
                const float* zr = ht + kl * ZSTR + ml0;
                float4 a0 = *(const float4*)(zr);
                float4 a1 = *(const float4*)(zr + 4);
                float av[8] = {a0.x, a0.y, a0.z, a0.w, a1.x, a1.y, a1.z, a1.w};
                #pragma unroll
                for (int i = 0; i < 8; ++i) {
                    acc2[i][0] = fmaf(av[i], w4.x, acc2[i][0]);
                    acc2[i][1] = fmaf(av[i], w4.y, acc2[i][1]);
                    acc2[i][2] = fmaf(av[i], w4.z, acc2[i][2]);
                    acc2[i][3] = fmaf(av[i], w4.w, acc2[i][3]);
                }
            }
        }
    }
    if (act) {
        float4 b4 = *(const float4*)(bias + mhc * 4);
        #pragma unroll
        for (int i = 0; i < 8; ++i) {
            float4 o;
            o.x = acc2[i][0] + b4.x;
            o.y = acc2[i][1] + b4.y;
            o.z = acc2[i][2] + b4.z;
            o.w = acc2[i][3] + b4.w;
            *(float4*)(hb + (ml0 + i) * H + mhc * 4) = o;
        }
    }
}

// ---------------- fc1: partial[ks][b][p] = sum_{k in split} hd[b,k] * W[k,p] ----------------
__launch_bounds__(256, 3)
__global__ void fc1_kernel(const float* __restrict__ hd, const float* __restrict__ W,
                           float* __restrict__ partial)
{
    __shared__ float As[32 * 100];
    __shared__ float Bs[96 * 104];
    const int tid    = threadIdx.x;
    const int b0     = blockIdx.x * 32;
    const int ks     = blockIdx.y;
    const int kbase0 = ks * 2016;
    const bool act   = tid < 192;
    const int  bt    = tid / 24, pc = tid % 24;
    float acc[4][4];
    #pragma unroll
    for (int i = 0; i < 4; ++i) { acc[i][0] = acc[i][1] = acc[i][2] = acc[i][3] = 0.f; }

    for (int c = 0; c < 21; ++c) {
        int kb = kbase0 + c * 96;
        __syncthreads();
        for (int e = tid; e < 32 * 96; e += 256) {
            int r = e / 96, kk = e - r * 96;
            As[r * 100 + kk] = hd[(size_t)(b0 + r) * (L * H) + kb + kk];
        }
        for (int e = tid; e < 96 * 96; e += 256) {
            int kk = e / 96, p = e - kk * 96;
            Bs[kk * 104 + p] = W[(size_t)(kb + kk) * 96 + p];
        }
        __syncthreads();
        if (act) {
            #pragma unroll 4
            for (int kk = 0; kk < 96; ++kk) {
                float4 w4 = *(const float4*)(Bs + kk * 104 + pc * 4);
                #pragma unroll
                for (int i = 0; i < 4; ++i) {
                    float a = As[(bt * 4 + i) * 100 + kk];
                    acc[i][0] = fmaf(a, w4.x, acc[i][0]);
                    acc[i][1] = fmaf(a, w4.y, acc[i][1]);
                    acc[i][2] = fmaf(a, w4.z, acc[i][2]);
                    acc[i][3] = fmaf(a, w4.w, acc[i][3]);
                }
            }
        }
    }
    if (act) {
        #pragma unroll
        for (int i = 0; i < 4; ++i) {
            float* po = partial + (size_t)ks * (B * 96) + (size_t)(b0 + bt * 4 + i) * 96 + pc * 4;
            *(float4*)po = make_float4(acc[i][0], acc[i][1], acc[i][2], acc[i][3]);
        }
    }
}

__global__ void fc1red_kernel(const float* __restrict__ partial, const float* __restrict__ fb,
                              float* __restrict__ t1)
{
    int o = blockIdx.x * 256 + threadIdx.x;   // < 196608
    int p = o % 96;
    float s = fb[p];
    #pragma unroll
    for (int k = 0; k < 8; ++k) s += partial[(size_t)k * (B * 96) + o];
    t1[o] = s;
}

__launch_bounds__(256)
__global__ void fc2_kernel(const float* __restrict__ t1, const float* __restrict__ W,
                           const float* __restrict__ fb, float* __restrict__ out)
{
    __shared__ float Ws[96 * 100];
    const int tid = threadIdx.x;
    for (int e = tid; e < 96 * 96; e += 256) Ws[(e / 96) * 100 + (e % 96)] = W[e];
    __syncthreads();
    int o = blockIdx.x * 256 + tid;
    int b = o / 96, p = o - b * 96;
    const float* tr = t1 + b * 96;
    float acc = fb[p];
    #pragma unroll 4
    for (int h = 0; h < 96; ++h) acc = fmaf(tr[h], Ws[h * 100 + p], acc);
    out[o] = acc;
}

extern "C" void kernel_launch(void* const* d_in, const int* in_sizes, int n_in,
                              void* d_out, int out_size, void* d_ws, size_t ws_size,
                              hipStream_t stream)
{
    const float* x      = (const float*)d_in[0];
    const float* encW   = (const float*)d_in[1];
    const float* encb   = (const float*)d_in[2];
    const float* log_dt = (const float*)d_in[3];
    const float* lar    = (const float*)d_in[4];
    const float* aim    = (const float*)d_in[5];
    const float* cre    = (const float*)d_in[6];
    const float* cim    = (const float*)d_in[7];
    const float* dsk    = (const float*)d_in[8];
    const float* wout   = (const float*)d_in[9];
    const float* boutp  = (const float*)d_in[10];
    const float* lnw    = (const float*)d_in[11];
    const float* lnb    = (const float*)d_in[12];
    const float* decW   = (const float*)d_in[13];
    const float* decb   = (const float*)d_in[14];
    const float* fc1W   = (const float*)d_in[15];
    const float* fc1b   = (const float*)d_in[16];
    const float* fc2W   = (const float*)d_in[17];
    const float* fc2b   = (const float*)d_in[18];

    char*  ws      = (char*)d_ws;
    float* K       = (float*)(ws);                      // 258 KB
    float* partial = (float*)(ws + (size_t)(1 << 19));  // 6.3 MB
    float* t1      = (float*)(ws + (size_t)(7 << 20));  // 786 KB
    float* hbuf    = (float*)(ws + (size_t)(16 << 20)); // 132 MB

    kgen_kernel<<<NB * H, 64, 0, stream>>>(log_dt, lar, aim, cre, cim, K);
    enc_kernel<<<2048, 256, 0, stream>>>(x, encW, encb, hbuf);
    for (int i = 0; i < NB; ++i) {
        s4_block<<<B, 512, 0, stream>>>(hbuf, K + i * H * L, wout + i * H * H,
                                        boutp + i * H, dsk + i * H, lnw + i * H, lnb + i * H);
    }
    dec_kernel<<<B, 512, 0, stream>>>(hbuf, decW, decb);
    fc1_kernel<<<dim3(64, 8), 256, 0, stream>>>(hbuf, fc1W, partial);
    fc1red_kernel<<<768, 256, 0, stream>>>(partial, fc1b, t1);
    fc2_kernel<<<768, 256, 0, stream>>>(t1, fc2W, fc2b, (float*)d_out);
}

// Round 4
// 1632.417 us; speedup vs baseline: 1.1599x; 1.1599x over previous
//
#include <hip/hip_runtime.h>
#include <hip/hip_bf16.h>
#include <math.h>

#define NB 4
#define B  2048
#define L  168
#define DI 9
#define H  96
#define N2 48

#define CH    32    // h-chunk (= MFMA K per chunk)
#define NCH   3
#define LSTR  188   // ut row stride (floats): 8 zero front pad + 168 + 12
#define Z2STR 178   // z2t row stride (u16 units, even -> aligned b32 writes, conflict-free)
#define NT    11    // n-tiles of 16 over l (168 -> 176 padded)

typedef short short8 __attribute__((ext_vector_type(8)));
typedef float f32x4  __attribute__((ext_vector_type(4)));

__device__ __forceinline__ float gelu_f(float x) {
    float x3 = x * x * x;
    float y  = 0.7978845608028654f * (x + 0.044715f * x3);
    float ey = __expf(2.0f * y);
    float t  = 1.0f - 2.0f / (ey + 1.0f);
    return 0.5f * x * (1.0f + t);
}

__device__ __forceinline__ unsigned short bf16_rne(float x) {
    unsigned u = __float_as_uint(x);
    return (unsigned short)((u + 0x7FFFu + ((u >> 16) & 1u)) >> 16);
}

// ---------------- S4D kernel generation: K[i][h][l] ----------------
__global__ void kgen_kernel(const float* __restrict__ log_dt, const float* __restrict__ lar,
                            const float* __restrict__ aim, const float* __restrict__ cre,
                            const float* __restrict__ cim, float* __restrict__ K)
{
    const int ih   = blockIdx.x;      // i*96+h, 384 blocks
    const int lane = threadIdx.x;     // 64
    float ctre = 0.f, ctim = 0.f, pre = 0.f, pim = 0.f, mre = 0.f, mim = 0.f;
    if (lane < N2) {
        float dt  = expf(log_dt[ih]);
        int   idx = ih * N2 + lane;
        float reA = -expf(lar[idx]);
        float imA = aim[idx];
        float dre = dt * reA, dim = dt * imA;
        float er  = expf(dre);
        float sv, cv;
        sincosf(dim, &sv, &cv);
        mre = er * cv; mim = er * sv;              // exp(dtA)
        float nre = mre - 1.0f, nim = mim;         // exp(dtA)-1
        float den = reA * reA + imA * imA;
        float tre = (nre * reA + nim * imA) / den; // (exp(dtA)-1)/A
        float tim = (nim * reA - nre * imA) / den;
        float cr = cre[idx], ci = cim[idx];
        ctre = cr * tre - ci * tim;                // Ct
        ctim = cr * tim + ci * tre;
        pre = 1.0f; pim = 0.0f;
    }
    float* Kr = K + ih * L;
    for (int l = 0; l < L; ++l) {
        float term = ctre * pre - ctim * pim;      // Re(Ct * p)
        #pragma unroll
        for (int off = 32; off > 0; off >>= 1) term += __shfl_xor(term, off, 64);
        if (lane == 0) Kr[l] = 2.0f * term;
        float nr = pre * mre - pim * mim;
        float ni = pre * mim + pim * mre;
        pre = nr; pim = ni;
    }
}

// ---------------- prepack W_out into MFMA A-fragments (hi/lo bf16 split) ----------------
// A[m-tile][row=c][k] = W[k][m*16+c];  layout: [layer][ch][m][s(hi/lo)][lane][4 dwords]
__global__ void wprep_kernel(const float* __restrict__ wout, short* __restrict__ wfrag)
{
    int idx = blockIdx.x * 256 + threadIdx.x;       // NB*9216 dword-tasks
    if (idx >= NB * 9216) return;
    int layer = idx / 9216;  int rem  = idx - layer * 9216;
    int ch    = rem / 3072;  int rem2 = rem - ch * 3072;
    int m     = rem2 / 512;  int rem3 = rem2 - m * 512;
    int s     = rem3 / 256;  int rem4 = rem3 - s * 256;
    int lane  = rem4 / 4;    int d    = rem4 - lane * 4;
    int g = lane >> 4, c = lane & 15;
    int k  = ch * 32 + g * 8 + 2 * d;
    int hp = m * 16 + c;
    const float* Wl = wout + layer * H * H;
    float w0 = Wl[k * H + hp];
    float w1 = Wl[(k + 1) * H + hp];
    unsigned short b0, b1;
    if (s == 0) { b0 = bf16_rne(w0); b1 = bf16_rne(w1); }
    else {
        unsigned short h0 = bf16_rne(w0), h1 = bf16_rne(w1);
        b0 = bf16_rne(w0 - __uint_as_float((unsigned)h0 << 16));
        b1 = bf16_rne(w1 - __uint_as_float((unsigned)h1 << 16));
    }
    wfrag[idx * 2]     = (short)b0;
    wfrag[idx * 2 + 1] = (short)b1;
}

// ---------------- encoder ----------------
__launch_bounds__(256)
__global__ void enc_kernel(const float* __restrict__ x, const float* __restrict__ W,
                           const float* __restrict__ bias, float* __restrict__ h)
{
    __shared__ float Ws[DI * H];
    __shared__ float bs[H];
    const int tid = threadIdx.x;
    for (int e = tid; e < DI * H; e += 256) Ws[e] = W[e];
    if (tid < H) bs[tid] = bias[tid];
    __syncthreads();
    const int total = B * L * H;
    for (int idx = blockIdx.x * 256 + tid; idx < total; idx += 2048 * 256) {
        int r = idx / H, c = idx - r * H;
        const float* xr = x + r * DI;
        float a = bs[c];
        #pragma unroll
        for (int k = 0; k < DI; ++k) a = fmaf(xr[k], Ws[k * H + c], a);
        h[idx] = a;
    }
}

// ---------------- fused S4 block: conv+skip -> gelu -> [MFMA z@W] -> +b +resid -> LN ----------------
__launch_bounds__(512, 2)
__global__ void s4_block(float* __restrict__ hbuf, const float* __restrict__ Kg,
                         const short* __restrict__ wfrag, const float* __restrict__ bout,
                         const float* __restrict__ Dsk, const float* __restrict__ lnw,
                         const float* __restrict__ lnb)
{
    __shared__ float ut[CH * LSTR];                 // 24064 B
    __shared__ unsigned short zhi[CH * Z2STR];      // 11392 B
    __shared__ unsigned short zlo[CH * Z2STR];      // 11392 B

    const int tid  = threadIdx.x;
    const int wave = tid >> 6;
    const int lane = tid & 63;
    const int g    = lane >> 4;
    const int c    = lane & 15;
    const int b    = blockIdx.x;
    float* __restrict__ hb = hbuf + (size_t)b * (L * H);

    // zero ut front pad + z2t l-padding (cols 168..175)
    for (int e = tid; e < CH * 8; e += 512) ut[(e >> 3) * LSTR + (e & 7)] = 0.0f;
    for (int e = tid; e < CH * 8; e += 512) {
        int r = e >> 3, col = 168 + (e & 7);
        zhi[r * Z2STR + col] = 0; zlo[r * Z2STR + col] = 0;
    }

    f32x4 acc[6][2];
    #pragma unroll
    for (int m = 0; m < 6; ++m)
        #pragma unroll
        for (int t = 0; t < 2; ++t) acc[m][t] = (f32x4){0.f, 0.f, 0.f, 0.f};

    for (int ch = 0; ch < NCH; ++ch) {
        __syncthreads();
        // stage u chunk (transposed): ut[kl][8+l] = u[l][ch*32+kl]
        for (int e = tid; e < CH * L; e += 512) {
            int l = e >> 5, kl = e & 31;
            ut[kl * LSTR + 8 + l] = hb[l * H + ch * CH + kl];
        }
        __syncthreads();
        // conv + skip + gelu -> z2t (hi/lo bf16), tasks = 21 l-tiles x 32 h
        for (int pass = 0; pass < 2; ++pass) {
            int task = tid + pass * 512;
            if (task < 672) {
                int lt = task >> 5, hl = task & 31;
                int l0 = lt * 8;
                int h  = ch * CH + hl;
                const float* Krow = Kg + h * L;
                const float* urow = ut + hl * LSTR;
                float accv[8] = {0, 0, 0, 0, 0, 0, 0, 0};
                for (int d0 = 0; d0 <= l0; d0 += 8) {
                    const float* up = urow + (l0 - d0);
                    float4 A0 = *(const float4*)(up);
                    float4 A1 = *(const float4*)(up + 4);
                    float4 A2 = *(const float4*)(up + 8);
                    float4 A3 = *(const float4*)(up + 12);
                    float uv[16] = {A0.x, A0.y, A0.z, A0.w, A1.x, A1.y, A1.z, A1.w,
                                    A2.x, A2.y, A2.z, A2.w, A3.x, A3.y, A3.z, A3.w};
                    float4 K0 = *(const float4*)(Krow + d0);
                    float4 K1 = *(const float4*)(Krow + d0 + 4);
                    float kv[8] = {K0.x, K0.y, K0.z, K0.w, K1.x, K1.y, K1.z, K1.w};
                    #pragma unroll
                    for (int dd = 0; dd < 8; ++dd) {
                        #pragma unroll
                        for (int i = 0; i < 8; ++i)
                            accv[i] = fmaf(kv[dd], uv[8 + i - dd], accv[i]);
                    }
                }
                float  ds = Dsk[h];
                float4 U0 = *(const float4*)(urow + 8 + l0);
                float4 U1 = *(const float4*)(urow + 12 + l0);
                float uc[8] = {U0.x, U0.y, U0.z, U0.w, U1.x, U1.y, U1.z, U1.w};
                float zo[8];
                #pragma unroll
                for (int i = 0; i < 8; ++i) zo[i] = gelu_f(fmaf(ds, uc[i], accv[i]));
                // split to bf16 hi/lo, packed b32 stores (aligned: Z2STR even, l0 even)
                unsigned* zh32 = (unsigned*)&zhi[hl * Z2STR + l0];
                unsigned* zl32 = (unsigned*)&zlo[hl * Z2STR + l0];
                #pragma unroll
                for (int p = 0; p < 4; ++p) {
                    float z0 = zo[2 * p], z1 = zo[2 * p + 1];
                    unsigned short h0 = bf16_rne(z0), h1 = bf16_rne(z1);
                    unsigned short q0 = bf16_rne(z0 - __uint_as_float((unsigned)h0 << 16));
                    unsigned short q1 = bf16_rne(z1 - __uint_as_float((unsigned)h1 << 16));
                    zh32[p] = (unsigned)h0 | ((unsigned)h1 << 16);
                    zl32[p] = (unsigned)q0 | ((unsigned)q1 << 16);
                }
            }
        }
        __syncthreads();
        // MFMA: OUT^T[h',l] += W^T chunk x z^T chunk (split-3 bf16)
        const short8* Wf = (const short8*)(wfrag) + (size_t)ch * 6 * 2 * 64;
        #pragma unroll
        for (int t = 0; t < 2; ++t) {
            int n = wave + 8 * t;
            if (n < NT) {
                int col = n * 16 + c;
                short8 bh, bl;
                #pragma unroll
                for (int j = 0; j < 8; ++j) {
                    int k = g * 8 + j;
                    bh[j] = (short)zhi[k * Z2STR + col];
                    bl[j] = (short)zlo[k * Z2STR + col];
                }
                #pragma unroll
                for (int m = 0; m < 6; ++m) {
                    short8 ah = Wf[(m * 2 + 0) * 64 + lane];
                    short8 al = Wf[(m * 2 + 1) * 64 + lane];
                    acc[m][t] = __builtin_amdgcn_mfma_f32_16x16x32_bf16(al, bh, acc[m][t], 0, 0, 0);
                    acc[m][t] = __builtin_amdgcn_mfma_f32_16x16x32_bf16(ah, bl, acc[m][t], 0, 0, 0);
                    acc[m][t] = __builtin_amdgcn_mfma_f32_16x16x32_bf16(ah, bh, acc[m][t], 0, 0, 0);
                }
            }
        }
    }
    // epilogue: + bias + residual -> LN -> store (each wave owns its own l rows)
    #pragma unroll
    for (int t = 0; t < 2; ++t) {
        int n = wave + 8 * t;
        if (n < NT) {
            int  l  = n * 16 + c;
            bool lv = (l < L);
            int  lc = lv ? l : (L - 1);
            float vals[6][4];
            float s = 0.f, q = 0.f;
            #pragma unroll
            for (int m = 0; m < 6; ++m) {
                float4 res = *(const float4*)(hb + lc * H + m * 16 + g * 4);
                float4 bo  = *(const float4*)(bout + m * 16 + g * 4);
                vals[m][0] = acc[m][t][0] + bo.x + res.x;
                vals[m][1] = acc[m][t][1] + bo.y + res.y;
                vals[m][2] = acc[m][t][2] + bo.z + res.z;
                vals[m][3] = acc[m][t][3] + bo.w + res.w;
                #pragma unroll
                for (int r = 0; r < 4; ++r) { s += vals[m][r]; q += vals[m][r] * vals[m][r]; }
            }
            s += __shfl_xor(s, 16, 64); q += __shfl_xor(q, 16, 64);
            s += __shfl_xor(s, 32, 64); q += __shfl_xor(q, 32, 64);
            float mean = s * (1.0f / 96.0f);
            float var  = q * (1.0f / 96.0f) - mean * mean;
            float rstd = rsqrtf(var + 1e-5f);
            if (lv) {
                #pragma unroll
                for (int m = 0; m < 6; ++m) {
                    float4 w4 = *(const float4*)(lnw + m * 16 + g * 4);
                    float4 b4 = *(const float4*)(lnb + m * 16 + g * 4);
                    float4 o;
                    o.x = fmaf((vals[m][0] - mean) * rstd, w4.x, b4.x);
                    o.y = fmaf((vals[m][1] - mean) * rstd, w4.y, b4.y);
                    o.z = fmaf((vals[m][2] - mean) * rstd, w4.z, b4.z);
                    o.w = fmaf((vals[m][3] - mean) * rstd, w4.w, b4.w);
                    *(float4*)(hb + l * H + m * 16 + g * 4) = o;
                }
            }
        }
    }
}

// ---------------- decoder: h = h @ dec_W + dec_b, in-place per b ----------------
#define DSTR 172
__launch_bounds__(512, 2)
__global__ void dec_kernel(float* __restrict__ hbuf, const float* __restrict__ Wg,
                           const float* __restrict__ bias)
{
    __shared__ float ht[32 * DSTR];
    const int tid = threadIdx.x;
    const int b   = blockIdx.x;
    float* __restrict__ hb = hbuf + (size_t)b * (L * H);
    const bool act = tid < 504;
    const int  mlt = tid / 24, mhc = tid - mlt * 24;
    const int  ml0 = mlt * 8;
    float acc2[8][4];
    #pragma unroll
    for (int i = 0; i < 8; ++i) { acc2[i][0] = acc2[i][1] = acc2[i][2] = acc2[i][3] = 0.f; }

    for (int ch = 0; ch < 3; ++ch) {
        __syncthreads();
        for (int e = tid; e < 32 * L; e += 512) {
            int l = e >> 5, kl = e & 31;
            ht[kl * DSTR + l] = hb[l * H + ch * 32 + kl];
        }
        __syncthreads();
        if (act) {
            const float* Wc = Wg + ch * 32 * H + mhc * 4;
            #pragma unroll 2
            for (int kl = 0; kl < 32; ++kl) {
                float4 w4 = *(const float4*)(Wc + kl * H);
                const float* zr = ht + kl * DSTR + ml0;
                float4 a0 = *(const float4*)(zr);
                float4 a1 = *(const float4*)(zr + 4);
                float av[8] = {a0.x, a0.y, a0.z, a0.w, a1.x, a1.y, a1.z, a1.w};
                #pragma unroll
                for (int i = 0; i < 8; ++i) {
                    acc2[i][0] = fmaf(av[i], w4.x, acc2[i][0]);
                    acc2[i][1] = fmaf(av[i], w4.y, acc2[i][1]);
                    acc2[i][2] = fmaf(av[i], w4.z, acc2[i][2]);
                    acc2[i][3] = fmaf(av[i], w4.w, acc2[i][3]);
                }
            }
        }
    }
    if (act) {
        float4 b4 = *(const float4*)(bias + mhc * 4);
        #pragma unroll
        for (int i = 0; i < 8; ++i) {
            float4 o;
            o.x = acc2[i][0] + b4.x;
            o.y = acc2[i][1] + b4.y;
            o.z = acc2[i][2] + b4.z;
            o.w = acc2[i][3] + b4.w;
            *(float4*)(hb + (ml0 + i) * H + mhc * 4) = o;
        }
    }
}

// ---------------- fc1 ----------------
__launch_bounds__(256, 3)
__global__ void fc1_kernel(const float* __restrict__ hd, const float* __restrict__ W,
                           float* __restrict__ partial)
{
    __shared__ float As[32 * 100];
    __shared__ float Bs[96 * 104];
    const int tid    = threadIdx.x;
    const int b0     = blockIdx.x * 32;
    const int ks     = blockIdx.y;
    const int kbase0 = ks * 2016;
    const bool act   = tid < 192;
    const int  bt    = tid / 24, pc = tid % 24;
    float acc[4][4];
    #pragma unroll
    for (int i = 0; i < 4; ++i) { acc[i][0] = acc[i][1] = acc[i][2] = acc[i][3] = 0.f; }

    for (int cc = 0; cc < 21; ++cc) {
        int kb = kbase0 + cc * 96;
        __syncthreads();
        for (int e = tid; e < 32 * 96; e += 256) {
            int r = e / 96, kk = e - r * 96;
            As[r * 100 + kk] = hd[(size_t)(b0 + r) * (L * H) + kb + kk];
        }
        for (int e = tid; e < 96 * 96; e += 256) {
            int kk = e / 96, p = e - kk * 96;
            Bs[kk * 104 + p] = W[(size_t)(kb + kk) * 96 + p];
        }
        __syncthreads();
        if (act) {
            #pragma unroll 4
            for (int kk = 0; kk < 96; ++kk) {
                float4 w4 = *(const float4*)(Bs + kk * 104 + pc * 4);
                #pragma unroll
                for (int i = 0; i < 4; ++i) {
                    float a = As[(bt * 4 + i) * 100 + kk];
                    acc[i][0] = fmaf(a, w4.x, acc[i][0]);
                    acc[i][1] = fmaf(a, w4.y, acc[i][1]);
                    acc[i][2] = fmaf(a, w4.z, acc[i][2]);
                    acc[i][3] = fmaf(a, w4.w, acc[i][3]);
                }
            }
        }
    }
    if (act) {
        #pragma unroll
        for (int i = 0; i < 4; ++i) {
            float* po = partial + (size_t)ks * (B * 96) + (size_t)(b0 + bt * 4 + i) * 96 + pc * 4;
            *(float4*)po = make_float4(acc[i][0], acc[i][1], acc[i][2], acc[i][3]);
        }
    }
}

__global__ void fc1red_kernel(const float* __restrict__ partial, const float* __restrict__ fb,
                              float* __restrict__ t1)
{
    int o = blockIdx.x * 256 + threadIdx.x;   // < 196608
    int p = o % 96;
    float s = fb[p];
    #pragma unroll
    for (int k = 0; k < 8; ++k) s += partial[(size_t)k * (B * 96) + o];
    t1[o] = s;
}

__launch_bounds__(256)
__global__ void fc2_kernel(const float* __restrict__ t1, const float* __restrict__ W,
                           const float* __restrict__ fb, float* __restrict__ out)
{
    __shared__ float Ws[96 * 100];
    const int tid = threadIdx.x;
    for (int e = tid; e < 96 * 96; e += 256) Ws[(e / 96) * 100 + (e % 96)] = W[e];
    __syncthreads();
    int o = blockIdx.x * 256 + tid;
    int b = o / 96, p = o - b * 96;
    const float* tr = t1 + b * 96;
    float acc = fb[p];
    #pragma unroll 4
    for (int h = 0; h < 96; ++h) acc = fmaf(tr[h], Ws[h * 100 + p], acc);
    out[o] = acc;
}

extern "C" void kernel_launch(void* const* d_in, const int* in_sizes, int n_in,
                              void* d_out, int out_size, void* d_ws, size_t ws_size,
                              hipStream_t stream)
{
    const float* x      = (const float*)d_in[0];
    const float* encW   = (const float*)d_in[1];
    const float* encb   = (const float*)d_in[2];
    const float* log_dt = (const float*)d_in[3];
    const float* lar    = (const float*)d_in[4];
    const float* aim    = (const float*)d_in[5];
    const float* cre    = (const float*)d_in[6];
    const float* cim    = (const float*)d_in[7];
    const float* dsk    = (const float*)d_in[8];
    const float* wout   = (const float*)d_in[9];
    const float* boutp  = (const float*)d_in[10];
    const float* lnw    = (const float*)d_in[11];
    const float* lnb    = (const float*)d_in[12];
    const float* decW   = (const float*)d_in[13];
    const float* decb   = (const float*)d_in[14];
    const float* fc1W   = (const float*)d_in[15];
    const float* fc1b   = (const float*)d_in[16];
    const float* fc2W   = (const float*)d_in[17];
    const float* fc2b   = (const float*)d_in[18];

    char*  ws      = (char*)d_ws;
    float* K       = (float*)(ws);                       // 258 KB
    short* wfrag   = (short*)(ws + (size_t)(512 << 10)); // 144 KB (73728 shorts)
    float* partial = (float*)(ws + (size_t)(2 << 20));   // 6.3 MB
    float* t1      = (float*)(ws + (size_t)(9 << 20));   // 786 KB
    float* hbuf    = (float*)(ws + (size_t)(16 << 20));  // 132 MB

    kgen_kernel<<<NB * H, 64, 0, stream>>>(log_dt, lar, aim, cre, cim, K);
    wprep_kernel<<<144, 256, 0, stream>>>(wout, wfrag);
    enc_kernel<<<2048, 256, 0, stream>>>(x, encW, encb, hbuf);
    for (int i = 0; i < NB; ++i) {
        // per-layer stride = 9216 tasks * 2 shorts = 18432 shorts (fix: was 36864)
        s4_block<<<B, 512, 0, stream>>>(hbuf, K + i * H * L, wfrag + i * 18432,
                                        boutp + i * H, dsk + i * H, lnw + i * H, lnb + i * H);
    }
    dec_kernel<<<B, 512, 0, stream>>>(hbuf, decW, decb);
    fc1_kernel<<<dim3(64, 8), 256, 0, stream>>>(hbuf, fc1W, partial);
    fc1red_kernel<<<768, 256, 0, stream>>>(partial, fc1b, t1);
    fc2_kernel<<<768, 256, 0, stream>>>(t1, fc2W, fc2b, (float*)d_out);
}

// Round 6
// 1034.928 us; speedup vs baseline: 1.8296x; 1.5773x over previous
//
#include <hip/hip_runtime.h>
#include <hip/hip_bf16.h>
#include <math.h>

#define NB 4
#define B  2048
#define L  168
#define DI 9
#define H  96
#define N2 48

#define USTR  196   // conv u row stride (floats): 16 front pad + 168 + 12
#define ZSTR2 132   // mix/dec zs row stride (ushorts): 128 + 4 pad

typedef short short8 __attribute__((ext_vector_type(8)));
typedef float f32x4  __attribute__((ext_vector_type(4)));
typedef unsigned short u16x8 __attribute__((ext_vector_type(8)));
typedef unsigned short u16x4 __attribute__((ext_vector_type(4)));

__device__ __forceinline__ float gelu_f(float x) {
    float x3 = x * x * x;
    float y  = 0.7978845608028654f * (x + 0.044715f * x3);
    float ey = __expf(2.0f * y);
    float t  = 1.0f - 2.0f / (ey + 1.0f);
    return 0.5f * x * (1.0f + t);
}

__device__ __forceinline__ unsigned short bf16_rne(float x) {
    unsigned u = __float_as_uint(x);
    return (unsigned short)((u + 0x7FFFu + ((u >> 16) & 1u)) >> 16);
}
__device__ __forceinline__ float b2f(unsigned short v) {
    return __uint_as_float((unsigned)v << 16);
}

// ---------------- S4D kernel generation: K[i][h][l] ----------------
__global__ void kgen_kernel(const float* __restrict__ log_dt, const float* __restrict__ lar,
                            const float* __restrict__ aim, const float* __restrict__ cre,
                            const float* __restrict__ cim, float* __restrict__ K)
{
    const int ih   = blockIdx.x;
    const int lane = threadIdx.x;
    float ctre = 0.f, ctim = 0.f, pre = 0.f, pim = 0.f, mre = 0.f, mim = 0.f;
    if (lane < N2) {
        float dt  = expf(log_dt[ih]);
        int   idx = ih * N2 + lane;
        float reA = -expf(lar[idx]);
        float imA = aim[idx];
        float dre = dt * reA, dim = dt * imA;
        float er  = expf(dre);
        float sv, cv;
        sincosf(dim, &sv, &cv);
        mre = er * cv; mim = er * sv;
        float nre = mre - 1.0f, nim = mim;
        float den = reA * reA + imA * imA;
        float tre = (nre * reA + nim * imA) / den;
        float tim = (nim * reA - nre * imA) / den;
        float cr = cre[idx], ci = cim[idx];
        ctre = cr * tre - ci * tim;
        ctim = cr * tim + ci * tre;
        pre = 1.0f; pim = 0.0f;
    }
    float* Kr = K + ih * L;
    for (int l = 0; l < L; ++l) {
        float term = ctre * pre - ctim * pim;
        #pragma unroll
        for (int off = 32; off > 0; off >>= 1) term += __shfl_xor(term, off, 64);
        if (lane == 0) Kr[l] = 2.0f * term;
        float nr = pre * mre - pim * mim;
        float ni = pre * mim + pim * mre;
        pre = nr; pim = ni;
    }
}

// ---------------- prepack W (96x96, row=k, col=h') into MFMA A-fragments hi/lo ----------------
__global__ void wprep_kernel(const float* __restrict__ wout, short* __restrict__ wfrag, int ntask)
{
    int idx = blockIdx.x * 256 + threadIdx.x;
    if (idx >= ntask) return;
    int layer = idx / 9216;  int rem  = idx - layer * 9216;
    int ch    = rem / 3072;  int rem2 = rem - ch * 3072;
    int m     = rem2 / 512;  int rem3 = rem2 - m * 512;
    int s     = rem3 / 256;  int rem4 = rem3 - s * 256;
    int lane  = rem4 / 4;    int d    = rem4 - lane * 4;
    int g = lane >> 4, c = lane & 15;
    int k  = ch * 32 + g * 8 + 2 * d;
    int hp = m * 16 + c;
    const float* Wl = wout + layer * H * H;
    float w0 = Wl[k * H + hp];
    float w1 = Wl[(k + 1) * H + hp];
    unsigned short b0, b1;
    if (s == 0) { b0 = bf16_rne(w0); b1 = bf16_rne(w1); }
    else {
        unsigned short h0 = bf16_rne(w0), h1 = bf16_rne(w1);
        b0 = bf16_rne(w0 - b2f(h0));
        b1 = bf16_rne(w1 - b2f(h1));
    }
    wfrag[idx * 2]     = (short)b0;
    wfrag[idx * 2 + 1] = (short)b1;
}

// ---------------- encoder into (h,l,b) bf16 ----------------
__launch_bounds__(256)
__global__ void enc2_kernel(const float* __restrict__ x, const float* __restrict__ W,
                            const float* __restrict__ bias, unsigned short* __restrict__ hb2)
{
    __shared__ float Ws[DI * H];
    __shared__ float bs[H];
    const int tid = threadIdx.x;
    const int l   = blockIdx.x;
    const int b0  = blockIdx.y * 256;
    for (int e = tid; e < DI * H; e += 256) Ws[e] = W[e];
    if (tid < H) bs[tid] = bias[tid];
    __syncthreads();
    float xv[DI];
    const float* xr = x + (size_t)(b0 + tid) * (L * DI) + l * DI;
    #pragma unroll
    for (int k = 0; k < DI; ++k) xv[k] = xr[k];
    for (int h = 0; h < H; ++h) {
        float a = bs[h];
        #pragma unroll
        for (int k = 0; k < DI; ++k) a = fmaf(xv[k], Ws[k * H + h], a);
        hb2[((size_t)h * L + l) * B + b0 + tid] = bf16_rne(a);
    }
}

// ---------------- conv (depthwise causal) + skip + GELU: fp32 VALU, bf16 in/out ----------------
__launch_bounds__(256)
__global__ void conv2_kernel(const unsigned short* __restrict__ hb2, const float* __restrict__ Kg,
                             const float* __restrict__ Dsk, unsigned short* __restrict__ z2)
{
    __shared__ __align__(16) float us[64 * USTR];
    __shared__ __align__(16) float Ks[176];
    const int tid = threadIdx.x;
    const int c   = tid >> 6;
    const int bb  = tid & 63;
    const int h   = blockIdx.x;
    const int b0  = blockIdx.y * 64;
    const unsigned short* ub = hb2 + (size_t)h * L * B + b0;

    // zero pads (front 16, tail 12)
    for (int e = tid; e < 64 * 28; e += 256) {
        int r = e / 28, j = e - r * 28;
        int idx = (j < 16) ? j : (184 + (j - 16));
        us[r * USTR + idx] = 0.0f;
    }
    // stage u (bf16 -> fp32): pairs of b per thread, coalesced 128B rows
    for (int e = tid; e < L * 32; e += 256) {
        int l = e >> 5, bp = e & 31;
        unsigned v = *(const unsigned*)(ub + (size_t)l * B + 2 * bp);
        us[(2 * bp) * USTR + 16 + l]     = b2f((unsigned short)(v & 0xffffu));
        us[(2 * bp + 1) * USTR + 16 + l] = b2f((unsigned short)(v >> 16));
    }
    if (tid < 176) Ks[tid] = (tid < L) ? Kg[h * L + tid] : 0.0f;
    __syncthreads();

    const float ds = Dsk[h];
    const float* ur = us + bb * USTR;
    unsigned short* zb = z2 + (size_t)h * L * B + b0 + bb;
    // l-tile -> wave map balancing triangular work: sums 32/32/34/34
    const int cmap[11] = {2, 3, 3, 3, 0, 1, 2, 3, 2, 1, 0};

    #pragma unroll
    for (int lt = 0; lt < 11; ++lt) {
        if (cmap[lt] != c) continue;
        const int l0 = lt * 16;
        float acc[16];
        #pragma unroll
        for (int i = 0; i < 16; ++i) acc[i] = 0.f;
        for (int d0 = 0; d0 <= l0 + 8; d0 += 8) {
            float4 K0 = *(const float4*)(Ks + d0);
            float4 K1 = *(const float4*)(Ks + d0 + 4);
            float kv[8] = {K0.x, K0.y, K0.z, K0.w, K1.x, K1.y, K1.z, K1.w};
            const float* up = ur + (8 + l0 - d0);
            float4 A0 = *(const float4*)(up);
            float4 A1 = *(const float4*)(up + 4);
            float4 A2 = *(const float4*)(up + 8);
            float4 A3 = *(const float4*)(up + 12);
            float4 A4 = *(const float4*)(up + 16);
            float4 A5 = *(const float4*)(up + 20);
            float uv[24] = {A0.x, A0.y, A0.z, A0.w, A1.x, A1.y, A1.z, A1.w,
                            A2.x, A2.y, A2.z, A2.w, A3.x, A3.y, A3.z, A3.w,
                            A4.x, A4.y, A4.z, A4.w, A5.x, A5.y, A5.z, A5.w};
            #pragma unroll
            for (int dd = 0; dd < 8; ++dd)
                #pragma unroll
                for (int i = 0; i < 16; ++i)
                    acc[i] = fmaf(kv[dd], uv[8 + i - dd], acc[i]);
        }
        #pragma unroll
        for (int i = 0; i < 16; i += 4) {
            float4 U = *(const float4*)(ur + 16 + l0 + i);
            float uu[4] = {U.x, U.y, U.z, U.w};
            #pragma unroll
            for (int r = 0; r < 4; ++r) {
                int l = l0 + i + r;
                if (l < L) {
                    float z = gelu_f(fmaf(ds, uu[r], acc[i + r]));
                    zb[(size_t)l * B] = bf16_rne(z);
                }
            }
        }
    }
}

// ---------------- W_out GEMM (MFMA, W split-2) + bias + residual + LN ----------------
__launch_bounds__(256)
__global__ void mix2_kernel(const unsigned short* __restrict__ z2, unsigned short* __restrict__ hb2,
                            const short* __restrict__ wfrag, const float* __restrict__ bout,
                            const float* __restrict__ lnw, const float* __restrict__ lnb)
{
    __shared__ __align__(16) unsigned short zs[H * ZSTR2];
    const int tid  = threadIdx.x;
    const int w    = tid >> 6;
    const int lane = tid & 63;
    const int g    = lane >> 4;
    const int cc   = lane & 15;
    const int l    = blockIdx.x;
    const int b0   = blockIdx.y * 128;

    for (int e = tid; e < 96 * 16; e += 256) {
        int hh = e >> 4, b8 = e & 15;
        u16x8 v = *(const u16x8*)(z2 + ((size_t)hh * L + l) * B + b0 + b8 * 8);
        *(u16x4*)(&zs[hh * ZSTR2 + b8 * 8])     = (u16x4){v[0], v[1], v[2], v[3]};
        *(u16x4*)(&zs[hh * ZSTR2 + b8 * 8 + 4]) = (u16x4){v[4], v[5], v[6], v[7]};
    }
    __syncthreads();

    f32x4 acc[2][6];
    #pragma unroll
    for (int n2 = 0; n2 < 2; ++n2)
        #pragma unroll
        for (int m = 0; m < 6; ++m) acc[n2][m] = (f32x4){0.f, 0.f, 0.f, 0.f};

    for (int ks = 0; ks < 3; ++ks) {
        short8 bh[2];
        #pragma unroll
        for (int n2 = 0; n2 < 2; ++n2) {
            int col = (w * 2 + n2) * 16 + cc;
            #pragma unroll
            for (int j = 0; j < 8; ++j)
                bh[n2][j] = (short)zs[(ks * 32 + g * 8 + j) * ZSTR2 + col];
        }
        const short8* Wf = (const short8*)(wfrag) + ks * 12 * 64;
        #pragma unroll
        for (int m = 0; m < 6; ++m) {
            short8 ah = Wf[(m * 2 + 0) * 64 + lane];
            short8 al = Wf[(m * 2 + 1) * 64 + lane];
            #pragma unroll
            for (int n2 = 0; n2 < 2; ++n2) {
                acc[n2][m] = __builtin_amdgcn_mfma_f32_16x16x32_bf16(al, bh[n2], acc[n2][m], 0, 0, 0);
                acc[n2][m] = __builtin_amdgcn_mfma_f32_16x16x32_bf16(ah, bh[n2], acc[n2][m], 0, 0, 0);
            }
        }
    }

    #pragma unroll
    for (int n2 = 0; n2 < 2; ++n2) {
        int gb = b0 + (w * 2 + n2) * 16 + cc;
        float vals[6][4];
        float s = 0.f, q = 0.f;
        #pragma unroll
        for (int m = 0; m < 6; ++m) {
            float4 B4 = *(const float4*)(bout + m * 16 + g * 4);
            float bo[4] = {B4.x, B4.y, B4.z, B4.w};
            #pragma unroll
            for (int r = 0; r < 4; ++r) {
                int hr = m * 16 + g * 4 + r;
                float res = b2f(hb2[((size_t)hr * L + l) * B + gb]);
                float v = acc[n2][m][r] + bo[r] + res;
                vals[m][r] = v;
                s += v; q += v * v;
            }
        }
        s += __shfl_xor(s, 16, 64); q += __shfl_xor(q, 16, 64);
        s += __shfl_xor(s, 32, 64); q += __shfl_xor(q, 32, 64);
        float mean = s * (1.0f / 96.0f);
        float var  = q * (1.0f / 96.0f) - mean * mean;
        float rstd = rsqrtf(var + 1e-5f);
        #pragma unroll
        for (int m = 0; m < 6; ++m) {
            float4 W4 = *(const float4*)(lnw + m * 16 + g * 4);
            float4 Bb = *(const float4*)(lnb + m * 16 + g * 4);
            float wv[4] = {W4.x, W4.y, W4.z, W4.w};
            float bv[4] = {Bb.x, Bb.y, Bb.z, Bb.w};
            #pragma unroll
            for (int r = 0; r < 4; ++r) {
                int hr = m * 16 + g * 4 + r;
                hb2[((size_t)hr * L + l) * B + gb] =
                    bf16_rne(fmaf((vals[m][r] - mean) * rstd, wv[r], bv[r]));
            }
        }
    }
}

// ---------------- decoder GEMM (MFMA, W split-2) + bias, in-place on hb2 ----------------
__launch_bounds__(256)
__global__ void dec2_kernel(unsigned short* __restrict__ hb2, const short* __restrict__ wfrag,
                            const float* __restrict__ bias)
{
    __shared__ __align__(16) unsigned short zs[H * ZSTR2];
    const int tid  = threadIdx.x;
    const int w    = tid >> 6;
    const int lane = tid & 63;
    const int g    = lane >> 4;
    const int cc   = lane & 15;
    const int l    = blockIdx.x;
    const int b0   = blockIdx.y * 128;

    for (int e = tid; e < 96 * 16; e += 256) {
        int hh = e >> 4, b8 = e & 15;
        u16x8 v = *(const u16x8*)(hb2 + ((size_t)hh * L + l) * B + b0 + b8 * 8);
        *(u16x4*)(&zs[hh * ZSTR2 + b8 * 8])     = (u16x4){v[0], v[1], v[2], v[3]};
        *(u16x4*)(&zs[hh * ZSTR2 + b8 * 8 + 4]) = (u16x4){v[4], v[5], v[6], v[7]};
    }
    __syncthreads();

    f32x4 acc[2][6];
    #pragma unroll
    for (int n2 = 0; n2 < 2; ++n2)
        #pragma unroll
        for (int m = 0; m < 6; ++m) acc[n2][m] = (f32x4){0.f, 0.f, 0.f, 0.f};

    for (int ks = 0; ks < 3; ++ks) {
        short8 bh[2];
        #pragma unroll
        for (int n2 = 0; n2 < 2; ++n2) {
            int col = (w * 2 + n2) * 16 + cc;
            #pragma unroll
            for (int j = 0; j < 8; ++j)
                bh[n2][j] = (short)zs[(ks * 32 + g * 8 + j) * ZSTR2 + col];
        }
        const short8* Wf = (const short8*)(wfrag) + ks * 12 * 64;
        #pragma unroll
        for (int m = 0; m < 6; ++m) {
            short8 ah = Wf[(m * 2 + 0) * 64 + lane];
            short8 al = Wf[(m * 2 + 1) * 64 + lane];
            #pragma unroll
            for (int n2 = 0; n2 < 2; ++n2) {
                acc[n2][m] = __builtin_amdgcn_mfma_f32_16x16x32_bf16(al, bh[n2], acc[n2][m], 0, 0, 0);
                acc[n2][m] = __builtin_amdgcn_mfma_f32_16x16x32_bf16(ah, bh[n2], acc[n2][m], 0, 0, 0);
            }
        }
    }

    #pragma unroll
    for (int n2 = 0; n2 < 2; ++n2) {
        int gb = b0 + (w * 2 + n2) * 16 + cc;
        #pragma unroll
        for (int m = 0; m < 6; ++m) {
            float4 B4 = *(const float4*)(bias + m * 16 + g * 4);
            float bo[4] = {B4.x, B4.y, B4.z, B4.w};
            #pragma unroll
            for (int r = 0; r < 4; ++r) {
                int hr = m * 16 + g * 4 + r;
                hb2[((size_t)hr * L + l) * B + gb] = bf16_rne(acc[n2][m][r] + bo[r]);
            }
        }
    }
}

// ---------------- fc1: split-K partials, reads hb2 bf16 (h,l,b); k = l*96+h ----------------
__launch_bounds__(256)
__global__ void fc1_kernel(const unsigned short* __restrict__ hd, const float* __restrict__ W,
                           float* __restrict__ partial)
{
    __shared__ float As[96 * 33];
    __shared__ float Bs[96 * 104];
    const int tid = threadIdx.x;
    const int b0  = blockIdx.x * 32;
    const int ks  = blockIdx.y;
    const bool act = tid < 192;
    const int bt = tid / 24, pc = tid % 24;
    float acc[4][4];
    #pragma unroll
    for (int i = 0; i < 4; ++i) { acc[i][0] = acc[i][1] = acc[i][2] = acc[i][3] = 0.f; }

    for (int cc2 = 0; cc2 < 21; ++cc2) {
        int l = ks * 21 + cc2;
        __syncthreads();
        for (int e = tid; e < 96 * 32; e += 256) {
            int kk = e >> 5, b = e & 31;
            As[kk * 33 + b] = b2f(hd[((size_t)kk * L + l) * B + b0 + b]);
        }
        for (int e = tid; e < 96 * 96; e += 256) {
            int kk = e / 96, p = e - kk * 96;
            Bs[kk * 104 + p] = W[(size_t)(l * 96 + kk) * 96 + p];
        }
        __syncthreads();
        if (act) {
            #pragma unroll 4
            for (int kk = 0; kk < 96; ++kk) {
                float4 w4 = *(const float4*)(Bs + kk * 104 + pc * 4);
                #pragma unroll
                for (int i = 0; i < 4; ++i) {
                    float a = As[kk * 33 + bt * 4 + i];
                    acc[i][0] = fmaf(a, w4.x, acc[i][0]);
                    acc[i][1] = fmaf(a, w4.y, acc[i][1]);
                    acc[i][2] = fmaf(a, w4.z, acc[i][2]);
                    acc[i][3] = fmaf(a, w4.w, acc[i][3]);
                }
            }
        }
    }
    if (act) {
        #pragma unroll
        for (int i = 0; i < 4; ++i) {
            float* po = partial + (size_t)ks * (B * 96) + (size_t)(b0 + bt * 4 + i) * 96 + pc * 4;
            *(float4*)po = make_float4(acc[i][0], acc[i][1], acc[i][2], acc[i][3]);
        }
    }
}

__global__ void fc1red_kernel(const float* __restrict__ partial, const float* __restrict__ fb,
                              float* __restrict__ t1)
{
    int o = blockIdx.x * 256 + threadIdx.x;
    int p = o % 96;
    float s = fb[p];
    #pragma unroll
    for (int k = 0; k < 8; ++k) s += partial[(size_t)k * (B * 96) + o];
    t1[o] = s;
}

__launch_bounds__(256)
__global__ void fc2_kernel(const float* __restrict__ t1, const float* __restrict__ W,
                           const float* __restrict__ fb, float* __restrict__ out)
{
    __shared__ float Ws[96 * 100];
    const int tid = threadIdx.x;
    for (int e = tid; e < 96 * 96; e += 256) Ws[(e / 96) * 100 + (e % 96)] = W[e];
    __syncthreads();
    int o = blockIdx.x * 256 + tid;
    int b = o / 96, p = o - b * 96;
    const float* tr = t1 + b * 96;
    float acc = fb[p];
    #pragma unroll 4
    for (int h = 0; h < 96; ++h) acc = fmaf(tr[h], Ws[h * 100 + p], acc);
    out[o] = acc;
}

extern "C" void kernel_launch(void* const* d_in, const int* in_sizes, int n_in,
                              void* d_out, int out_size, void* d_ws, size_t ws_size,
                              hipStream_t stream)
{
    const float* x      = (const float*)d_in[0];
    const float* encW   = (const float*)d_in[1];
    const float* encb   = (const float*)d_in[2];
    const float* log_dt = (const float*)d_in[3];
    const float* lar    = (const float*)d_in[4];
    const float* aim    = (const float*)d_in[5];
    const float* cre    = (const float*)d_in[6];
    const float* cim    = (const float*)d_in[7];
    const float* dsk    = (const float*)d_in[8];
    const float* wout   = (const float*)d_in[9];
    const float* boutp  = (const float*)d_in[10];
    const float* lnw    = (const float*)d_in[11];
    const float* lnb    = (const float*)d_in[12];
    const float* decW   = (const float*)d_in[13];
    const float* decb   = (const float*)d_in[14];
    const float* fc1W   = (const float*)d_in[15];
    const float* fc1b   = (const float*)d_in[16];
    const float* fc2W   = (const float*)d_in[17];
    const float* fc2b   = (const float*)d_in[18];

    // ws layout (total 143 MB, under the proven 148 MB budget):
    char*           ws      = (char*)d_ws;
    float*          K       = (float*)(ws);                        // 258 KB
    short*          wfrag   = (short*)(ws + (size_t)(512 << 10));  // 184 KB (4 wout + dec)
    float*          partial = (float*)(ws + (size_t)(1 << 20));    // 6.3 MB
    float*          t1      = (float*)(ws + (size_t)(8 << 20));    // 786 KB
    unsigned short* hb2     = (unsigned short*)(ws + (size_t)(16 << 20)); // 66.06 MB bf16 (h,l,b)
    unsigned short* z2      = (unsigned short*)(ws + (size_t)(80 << 20)); // 66.06 MB bf16 (h,l,b)

    kgen_kernel<<<NB * H, 64, 0, stream>>>(log_dt, lar, aim, cre, cim, K);
    wprep_kernel<<<144, 256, 0, stream>>>(wout, wfrag, NB * 9216);
    wprep_kernel<<<36, 256, 0, stream>>>(decW, wfrag + NB * 18432, 9216);
    enc2_kernel<<<dim3(L, 8), 256, 0, stream>>>(x, encW, encb, hb2);
    for (int i = 0; i < NB; ++i) {
        conv2_kernel<<<dim3(H, 32), 256, 0, stream>>>(hb2, K + i * H * L, dsk + i * H, z2);
        mix2_kernel<<<dim3(L, 16), 256, 0, stream>>>(z2, hb2, wfrag + i * 18432,
                                                     boutp + i * H, lnw + i * H, lnb + i * H);
    }
    dec2_kernel<<<dim3(L, 16), 256, 0, stream>>>(hb2, wfrag + NB * 18432, decb);
    fc1_kernel<<<dim3(64, 8), 256, 0, stream>>>(hb2, fc1W, partial);
    fc1red_kernel<<<768, 256, 0, stream>>>(partial, fc1b, t1);
    fc2_kernel<<<768, 256, 0, stream>>>(t1, fc2W, fc2b, (float*)d_out);
}

// Round 7
// 875.877 us; speedup vs baseline: 2.1619x; 1.1816x over previous
//
#include <hip/hip_runtime.h>
#include <hip/hip_bf16.h>
#include <math.h>

#define NB 4
#define B  2048
#define L  168
#define DI 9
#define H  96
#define N2 48

#define USTR  196   // conv u row stride (floats): 16 front pad + 168 + 12
#define ZSTR2 132   // mix/dec zs row stride (ushorts): 128 + 4 pad

typedef short short8 __attribute__((ext_vector_type(8)));
typedef float f32x4  __attribute__((ext_vector_type(4)));
typedef unsigned short u16x8 __attribute__((ext_vector_type(8)));
typedef unsigned short u16x4 __attribute__((ext_vector_type(4)));

__device__ __forceinline__ float gelu_f(float x) {
    float x3 = x * x * x;
    float y  = 0.7978845608028654f * (x + 0.044715f * x3);
    float ey = __expf(2.0f * y);
    float t  = 1.0f - 2.0f / (ey + 1.0f);
    return 0.5f * x * (1.0f + t);
}

__device__ __forceinline__ unsigned short bf16_rne(float x) {
    unsigned u = __float_as_uint(x);
    return (unsigned short)((u + 0x7FFFu + ((u >> 16) & 1u)) >> 16);
}
__device__ __forceinline__ float b2f(unsigned short v) {
    return __uint_as_float((unsigned)v << 16);
}

// ---------------- S4D kernel generation: K[i][h][l] ----------------
__global__ void kgen_kernel(const float* __restrict__ log_dt, const float* __restrict__ lar,
                            const float* __restrict__ aim, const float* __restrict__ cre,
                            const float* __restrict__ cim, float* __restrict__ K)
{
    const int ih   = blockIdx.x;
    const int lane = threadIdx.x;
    float ctre = 0.f, ctim = 0.f, pre = 0.f, pim = 0.f, mre = 0.f, mim = 0.f;
    if (lane < N2) {
        float dt  = expf(log_dt[ih]);
        int   idx = ih * N2 + lane;
        float reA = -expf(lar[idx]);
        float imA = aim[idx];
        float dre = dt * reA, dim = dt * imA;
        float er  = expf(dre);
        float sv, cv;
        sincosf(dim, &sv, &cv);
        mre = er * cv; mim = er * sv;
        float nre = mre - 1.0f, nim = mim;
        float den = reA * reA + imA * imA;
        float tre = (nre * reA + nim * imA) / den;
        float tim = (nim * reA - nre * imA) / den;
        float cr = cre[idx], ci = cim[idx];
        ctre = cr * tre - ci * tim;
        ctim = cr * tim + ci * tre;
        pre = 1.0f; pim = 0.0f;
    }
    float* Kr = K + ih * L;
    for (int l = 0; l < L; ++l) {
        float term = ctre * pre - ctim * pim;
        #pragma unroll
        for (int off = 32; off > 0; off >>= 1) term += __shfl_xor(term, off, 64);
        if (lane == 0) Kr[l] = 2.0f * term;
        float nr = pre * mre - pim * mim;
        float ni = pre * mim + pim * mre;
        pre = nr; pim = ni;
    }
}

// ---------------- prepack W (layers of 96x96, row=k, col=out) into MFMA A-frags hi/lo ----------------
__global__ void wprep_kernel(const float* __restrict__ wout, short* __restrict__ wfrag, int ntask)
{
    int idx = blockIdx.x * 256 + threadIdx.x;
    if (idx >= ntask) return;
    int layer = idx / 9216;  int rem  = idx - layer * 9216;
    int ch    = rem / 3072;  int rem2 = rem - ch * 3072;
    int m     = rem2 / 512;  int rem3 = rem2 - m * 512;
    int s     = rem3 / 256;  int rem4 = rem3 - s * 256;
    int lane  = rem4 / 4;    int d    = rem4 - lane * 4;
    int g = lane >> 4, c = lane & 15;
    int k  = ch * 32 + g * 8 + 2 * d;
    int hp = m * 16 + c;
    const float* Wl = wout + (size_t)layer * H * H;
    float w0 = Wl[k * H + hp];
    float w1 = Wl[(k + 1) * H + hp];
    unsigned short b0, b1;
    if (s == 0) { b0 = bf16_rne(w0); b1 = bf16_rne(w1); }
    else {
        unsigned short h0 = bf16_rne(w0), h1 = bf16_rne(w1);
        b0 = bf16_rne(w0 - b2f(h0));
        b1 = bf16_rne(w1 - b2f(h1));
    }
    wfrag[idx * 2]     = (short)b0;
    wfrag[idx * 2 + 1] = (short)b1;
}

// ---------------- compose decW into fc1W: Wcomp[l*96+k][p] = sum_h decW[k][h]*fc1W[l*96+h][p] ----------------
__launch_bounds__(256)
__global__ void wcomp_kernel(const float* __restrict__ decW, const float* __restrict__ decb,
                             const float* __restrict__ fc1W, float* __restrict__ wcs,
                             float* __restrict__ cbpart)
{
    __shared__ float Bs[96 * 100];
    const int tid = threadIdx.x;
    const int l   = blockIdx.x;
    for (int e = tid; e < 96 * 96; e += 256) {
        int h = e / 96, p = e - h * 96;
        Bs[h * 100 + p] = fc1W[(size_t)(l * 96 + h) * 96 + p];
    }
    __syncthreads();
    const int pt = tid & 31;
    const int kt = tid >> 5;        // 0..7
    float acc[12][3];
    #pragma unroll
    for (int kk = 0; kk < 12; ++kk)
        #pragma unroll
        for (int j = 0; j < 3; ++j) acc[kk][j] = 0.f;
    for (int h = 0; h < 96; ++h) {
        float dw[12];
        #pragma unroll
        for (int kk = 0; kk < 12; ++kk) dw[kk] = decW[(kt + 8 * kk) * 96 + h];
        float bs[3];
        #pragma unroll
        for (int j = 0; j < 3; ++j) bs[j] = Bs[h * 100 + pt + 32 * j];
        #pragma unroll
        for (int kk = 0; kk < 12; ++kk)
            #pragma unroll
            for (int j = 0; j < 3; ++j) acc[kk][j] = fmaf(dw[kk], bs[j], acc[kk][j]);
    }
    float* wl = wcs + (size_t)l * 9216;
    #pragma unroll
    for (int kk = 0; kk < 12; ++kk)
        #pragma unroll
        for (int j = 0; j < 3; ++j)
            wl[(kt + 8 * kk) * 96 + pt + 32 * j] = acc[kk][j];
    if (kt == 0) {
        #pragma unroll
        for (int j = 0; j < 3; ++j) {
            float s = 0.f;
            for (int h = 0; h < 96; ++h) s = fmaf(decb[h], Bs[h * 100 + pt + 32 * j], s);
            cbpart[l * 96 + pt + 32 * j] = s;
        }
    }
}

__global__ void cbias_red_kernel(const float* __restrict__ cbpart, const float* __restrict__ fc1b,
                                 float* __restrict__ cbias)
{
    int p = threadIdx.x;
    if (p < 96) {
        float s = fc1b[p];
        for (int l = 0; l < L; ++l) s += cbpart[l * 96 + p];
        cbias[p] = s;
    }
}

// ---------------- encoder into (h,l,b) bf16 ----------------
__launch_bounds__(256)
__global__ void enc2_kernel(const float* __restrict__ x, const float* __restrict__ W,
                            const float* __restrict__ bias, unsigned short* __restrict__ hb2)
{
    __shared__ float Ws[DI * H];
    __shared__ float bs[H];
    const int tid = threadIdx.x;
    const int l   = blockIdx.x;
    const int b0  = blockIdx.y * 256;
    for (int e = tid; e < DI * H; e += 256) Ws[e] = W[e];
    if (tid < H) bs[tid] = bias[tid];
    __syncthreads();
    float xv[DI];
    const float* xr = x + (size_t)(b0 + tid) * (L * DI) + l * DI;
    #pragma unroll
    for (int k = 0; k < DI; ++k) xv[k] = xr[k];
    for (int h = 0; h < H; ++h) {
        float a = bs[h];
        #pragma unroll
        for (int k = 0; k < DI; ++k) a = fmaf(xv[k], Ws[k * H + h], a);
        hb2[((size_t)h * L + l) * B + b0 + tid] = bf16_rne(a);
    }
}

// ---------------- conv (depthwise causal) + skip + GELU: fp32 VALU, bf16 in/out ----------------
__launch_bounds__(256)
__global__ void conv2_kernel(const unsigned short* __restrict__ hb2, const float* __restrict__ Kg,
                             const float* __restrict__ Dsk, unsigned short* __restrict__ z2)
{
    __shared__ __align__(16) float us[64 * USTR];
    __shared__ __align__(16) float Ks[176];
    const int tid = threadIdx.x;
    const int c   = tid >> 6;
    const int bb  = tid & 63;
    const int h   = blockIdx.x;
    const int b0  = blockIdx.y * 64;
    const unsigned short* ub = hb2 + (size_t)h * L * B + b0;

    for (int e = tid; e < 64 * 28; e += 256) {
        int r = e / 28, j = e - r * 28;
        int idx = (j < 16) ? j : (184 + (j - 16));
        us[r * USTR + idx] = 0.0f;
    }
    for (int e = tid; e < L * 32; e += 256) {
        int l = e >> 5, bp = e & 31;
        unsigned v = *(const unsigned*)(ub + (size_t)l * B + 2 * bp);
        us[(2 * bp) * USTR + 16 + l]     = b2f((unsigned short)(v & 0xffffu));
        us[(2 * bp + 1) * USTR + 16 + l] = b2f((unsigned short)(v >> 16));
    }
    if (tid < 176) Ks[tid] = (tid < L) ? Kg[h * L + tid] : 0.0f;
    __syncthreads();

    const float ds = Dsk[h];
    const float* ur = us + bb * USTR;
    unsigned short* zb = z2 + (size_t)h * L * B + b0 + bb;
    const int cmap[11] = {2, 3, 3, 3, 0, 1, 2, 3, 2, 1, 0};

    #pragma unroll
    for (int lt = 0; lt < 11; ++lt) {
        if (cmap[lt] != c) continue;
        const int l0 = lt * 16;
        float acc[16];
        #pragma unroll
        for (int i = 0; i < 16; ++i) acc[i] = 0.f;
        for (int d0 = 0; d0 <= l0 + 8; d0 += 8) {
            float4 K0 = *(const float4*)(Ks + d0);
            float4 K1 = *(const float4*)(Ks + d0 + 4);
            float kv[8] = {K0.x, K0.y, K0.z, K0.w, K1.x, K1.y, K1.z, K1.w};
            const float* up = ur + (8 + l0 - d0);
            float4 A0 = *(const float4*)(up);
            float4 A1 = *(const float4*)(up + 4);
            float4 A2 = *(const float4*)(up + 8);
            float4 A3 = *(const float4*)(up + 12);
            float4 A4 = *(const float4*)(up + 16);
            float4 A5 = *(const float4*)(up + 20);
            float uv[24] = {A0.x, A0.y, A0.z, A0.w, A1.x, A1.y, A1.z, A1.w,
                            A2.x, A2.y, A2.z, A2.w, A3.x, A3.y, A3.z, A3.w,
                            A4.x, A4.y, A4.z, A4.w, A5.x, A5.y, A5.z, A5.w};
            #pragma unroll
            for (int dd = 0; dd < 8; ++dd)
                #pragma unroll
                for (int i = 0; i < 16; ++i)
                    acc[i] = fmaf(kv[dd], uv[8 + i - dd], acc[i]);
        }
        #pragma unroll
        for (int i = 0; i < 16; i += 4) {
            float4 U = *(const float4*)(ur + 16 + l0 + i);
            float uu[4] = {U.x, U.y, U.z, U.w};
            #pragma unroll
            for (int r = 0; r < 4; ++r) {
                int l = l0 + i + r;
                if (l < L) {
                    float z = gelu_f(fmaf(ds, uu[r], acc[i + r]));
                    zb[(size_t)l * B] = bf16_rne(z);
                }
            }
        }
    }
}

// ---------------- W_out GEMM (MFMA, W split-2) + bias + residual + LN ----------------
__launch_bounds__(256)
__global__ void mix2_kernel(const unsigned short* __restrict__ z2, unsigned short* __restrict__ hb2,
                            const short* __restrict__ wfrag, const float* __restrict__ bout,
                            const float* __restrict__ lnw, const float* __restrict__ lnb)
{
    __shared__ __align__(16) unsigned short zs[H * ZSTR2];
    const int tid  = threadIdx.x;
    const int w    = tid >> 6;
    const int lane = tid & 63;
    const int g    = lane >> 4;
    const int cc   = lane & 15;
    const int l    = blockIdx.x;
    const int b0   = blockIdx.y * 128;

    for (int e = tid; e < 96 * 16; e += 256) {
        int hh = e >> 4, b8 = e & 15;
        u16x8 v = *(const u16x8*)(z2 + ((size_t)hh * L + l) * B + b0 + b8 * 8);
        *(u16x4*)(&zs[hh * ZSTR2 + b8 * 8])     = (u16x4){v[0], v[1], v[2], v[3]};
        *(u16x4*)(&zs[hh * ZSTR2 + b8 * 8 + 4]) = (u16x4){v[4], v[5], v[6], v[7]};
    }
    __syncthreads();

    f32x4 acc[2][6];
    #pragma unroll
    for (int n2 = 0; n2 < 2; ++n2)
        #pragma unroll
        for (int m = 0; m < 6; ++m) acc[n2][m] = (f32x4){0.f, 0.f, 0.f, 0.f};

    for (int ks = 0; ks < 3; ++ks) {
        short8 bh[2];
        #pragma unroll
        for (int n2 = 0; n2 < 2; ++n2) {
            int col = (w * 2 + n2) * 16 + cc;
            #pragma unroll
            for (int j = 0; j < 8; ++j)
                bh[n2][j] = (short)zs[(ks * 32 + g * 8 + j) * ZSTR2 + col];
        }
        const short8* Wf = (const short8*)(wfrag) + ks * 12 * 64;
        #pragma unroll
        for (int m = 0; m < 6; ++m) {
            short8 ah = Wf[(m * 2 + 0) * 64 + lane];
            short8 al = Wf[(m * 2 + 1) * 64 + lane];
            #pragma unroll
            for (int n2 = 0; n2 < 2; ++n2) {
                acc[n2][m] = __builtin_amdgcn_mfma_f32_16x16x32_bf16(al, bh[n2], acc[n2][m], 0, 0, 0);
                acc[n2][m] = __builtin_amdgcn_mfma_f32_16x16x32_bf16(ah, bh[n2], acc[n2][m], 0, 0, 0);
            }
        }
    }

    #pragma unroll
    for (int n2 = 0; n2 < 2; ++n2) {
        int gb = b0 + (w * 2 + n2) * 16 + cc;
        float vals[6][4];
        float s = 0.f, q = 0.f;
        #pragma unroll
        for (int m = 0; m < 6; ++m) {
            float4 B4 = *(const float4*)(bout + m * 16 + g * 4);
            float bo[4] = {B4.x, B4.y, B4.z, B4.w};
            #pragma unroll
            for (int r = 0; r < 4; ++r) {
                int hr = m * 16 + g * 4 + r;
                float res = b2f(hb2[((size_t)hr * L + l) * B + gb]);
                float v = acc[n2][m][r] + bo[r] + res;
                vals[m][r] = v;
                s += v; q += v * v;
            }
        }
        s += __shfl_xor(s, 16, 64); q += __shfl_xor(q, 16, 64);
        s += __shfl_xor(s, 32, 64); q += __shfl_xor(q, 32, 64);
        float mean = s * (1.0f / 96.0f);
        float var  = q * (1.0f / 96.0f) - mean * mean;
        float rstd = rsqrtf(var + 1e-5f);
        #pragma unroll
        for (int m = 0; m < 6; ++m) {
            float4 W4 = *(const float4*)(lnw + m * 16 + g * 4);
            float4 Bb = *(const float4*)(lnb + m * 16 + g * 4);
            float wv[4] = {W4.x, W4.y, W4.z, W4.w};
            float bv[4] = {Bb.x, Bb.y, Bb.z, Bb.w};
            #pragma unroll
            for (int r = 0; r < 4; ++r) {
                int hr = m * 16 + g * 4 + r;
                hb2[((size_t)hr * L + l) * B + gb] =
                    bf16_rne(fmaf((vals[m][r] - mean) * rstd, wv[r], bv[r]));
            }
        }
    }
}

// ---------------- fc1 via MFMA with composed dec+fc1 weights, split-K over 42 ----------------
__launch_bounds__(256)
__global__ void fc1m_kernel(const unsigned short* __restrict__ hb2, const short* __restrict__ wcfrag,
                            float* __restrict__ partial)
{
    __shared__ __align__(16) unsigned short zs[H * ZSTR2];
    const int tid  = threadIdx.x;
    const int w    = tid >> 6;
    const int lane = tid & 63;
    const int g    = lane >> 4;
    const int cc   = lane & 15;
    const int ksp  = blockIdx.x;       // 0..41 (4 l's each)
    const int b0   = blockIdx.y * 128;

    f32x4 acc[2][6];
    #pragma unroll
    for (int n2 = 0; n2 < 2; ++n2)
        #pragma unroll
        for (int m = 0; m < 6; ++m) acc[n2][m] = (f32x4){0.f, 0.f, 0.f, 0.f};

    for (int il = 0; il < 4; ++il) {
        const int l = ksp * 4 + il;
        __syncthreads();
        for (int e = tid; e < 96 * 16; e += 256) {
            int hh = e >> 4, b8 = e & 15;
            u16x8 v = *(const u16x8*)(hb2 + ((size_t)hh * L + l) * B + b0 + b8 * 8);
            *(u16x4*)(&zs[hh * ZSTR2 + b8 * 8])     = (u16x4){v[0], v[1], v[2], v[3]};
            *(u16x4*)(&zs[hh * ZSTR2 + b8 * 8 + 4]) = (u16x4){v[4], v[5], v[6], v[7]};
        }
        __syncthreads();
        for (int ksl = 0; ksl < 3; ++ksl) {
            short8 bh[2];
            #pragma unroll
            for (int n2 = 0; n2 < 2; ++n2) {
                int col = (w * 2 + n2) * 16 + cc;
                #pragma unroll
                for (int j = 0; j < 8; ++j)
                    bh[n2][j] = (short)zs[(ksl * 32 + g * 8 + j) * ZSTR2 + col];
            }
            const short8* Wf = (const short8*)(wcfrag) + (size_t)(l * 3 + ksl) * 768;
            #pragma unroll
            for (int m = 0; m < 6; ++m) {
                short8 ah = Wf[(m * 2 + 0) * 64 + lane];
                short8 al = Wf[(m * 2 + 1) * 64 + lane];
                #pragma unroll
                for (int n2 = 0; n2 < 2; ++n2) {
                    acc[n2][m] = __builtin_amdgcn_mfma_f32_16x16x32_bf16(al, bh[n2], acc[n2][m], 0, 0, 0);
                    acc[n2][m] = __builtin_amdgcn_mfma_f32_16x16x32_bf16(ah, bh[n2], acc[n2][m], 0, 0, 0);
                }
            }
        }
    }

    #pragma unroll
    for (int n2 = 0; n2 < 2; ++n2) {
        int gb = b0 + (w * 2 + n2) * 16 + cc;
        #pragma unroll
        for (int m = 0; m < 6; ++m) {
            *(float4*)&partial[((size_t)ksp * B + gb) * 96 + m * 16 + g * 4] =
                make_float4(acc[n2][m][0], acc[n2][m][1], acc[n2][m][2], acc[n2][m][3]);
        }
    }
}

__global__ void fc1red_kernel(const float* __restrict__ partial, const float* __restrict__ cbias,
                              float* __restrict__ t1)
{
    int o = blockIdx.x * 256 + threadIdx.x;
    int p = o % 96;
    float s = cbias[p];
    #pragma unroll 6
    for (int k = 0; k < 42; ++k) s += partial[(size_t)k * (B * 96) + o];
    t1[o] = s;
}

__launch_bounds__(256)
__global__ void fc2_kernel(const float* __restrict__ t1, const float* __restrict__ W,
                           const float* __restrict__ fb, float* __restrict__ out)
{
    __shared__ float Ws[96 * 100];
    const int tid = threadIdx.x;
    for (int e = tid; e < 96 * 96; e += 256) Ws[(e / 96) * 100 + (e % 96)] = W[e];
    __syncthreads();
    int o = blockIdx.x * 256 + tid;
    int b = o / 96, p = o - b * 96;
    const float* tr = t1 + b * 96;
    float acc = fb[p];
    #pragma unroll 4
    for (int h = 0; h < 96; ++h) acc = fmaf(tr[h], Ws[h * 100 + p], acc);
    out[o] = acc;
}

extern "C" void kernel_launch(void* const* d_in, const int* in_sizes, int n_in,
                              void* d_out, int out_size, void* d_ws, size_t ws_size,
                              hipStream_t stream)
{
    const float* x      = (const float*)d_in[0];
    const float* encW   = (const float*)d_in[1];
    const float* encb   = (const float*)d_in[2];
    const float* log_dt = (const float*)d_in[3];
    const float* lar    = (const float*)d_in[4];
    const float* aim    = (const float*)d_in[5];
    const float* cre    = (const float*)d_in[6];
    const float* cim    = (const float*)d_in[7];
    const float* dsk    = (const float*)d_in[8];
    const float* wout   = (const float*)d_in[9];
    const float* boutp  = (const float*)d_in[10];
    const float* lnw    = (const float*)d_in[11];
    const float* lnb    = (const float*)d_in[12];
    const float* decW   = (const float*)d_in[13];
    const float* decb   = (const float*)d_in[14];
    const float* fc1W   = (const float*)d_in[15];
    const float* fc1b   = (const float*)d_in[16];
    const float* fc2W   = (const float*)d_in[17];
    const float* fc2b   = (const float*)d_in[18];

    // ws layout (max end ≈ 143 MiB, the round-6-proven envelope):
    char*           ws      = (char*)d_ws;
    float*          K       = (float*)(ws);                          // 258 KB
    short*          wfrag   = (short*)(ws + ((size_t)512 << 10));    // 147 KB (4 wout layers)
    float*          wcs     = (float*)(ws + ((size_t)1 << 20));      // 6.19 MB Wcomp fp32
    short*          wcfrag  = (short*)(ws + ((size_t)7 << 20));      // 6.19 MB Wcomp frags
    float*          cbpart  = (float*)(ws + ((size_t)13 << 20));     // 64.5 KB
    float*          cbias   = (float*)(ws + ((size_t)13 << 20) + (1 << 18)); // 384 B
    float*          t1      = (float*)(ws + ((size_t)14 << 20));     // 786 KB
    unsigned short* hb2     = (unsigned short*)(ws + ((size_t)16 << 20)); // 63 MiB bf16 (h,l,b)
    unsigned short* z2      = (unsigned short*)(ws + ((size_t)80 << 20)); // 63 MiB bf16 (h,l,b)
    float*          partial = (float*)(ws + ((size_t)80 << 20));     // 31.5 MiB, aliases z2 (dead by fc1)

    kgen_kernel<<<NB * H, 64, 0, stream>>>(log_dt, lar, aim, cre, cim, K);
    wprep_kernel<<<144, 256, 0, stream>>>(wout, wfrag, NB * 9216);
    wcomp_kernel<<<L, 256, 0, stream>>>(decW, decb, fc1W, wcs, cbpart);
    wprep_kernel<<<6048, 256, 0, stream>>>(wcs, wcfrag, L * 9216);
    cbias_red_kernel<<<1, 128, 0, stream>>>(cbpart, fc1b, cbias);
    enc2_kernel<<<dim3(L, 8), 256, 0, stream>>>(x, encW, encb, hb2);
    for (int i = 0; i < NB; ++i) {
        conv2_kernel<<<dim3(H, 32), 256, 0, stream>>>(hb2, K + i * H * L, dsk + i * H, z2);
        mix2_kernel<<<dim3(L, 16), 256, 0, stream>>>(z2, hb2, wfrag + i * 18432,
                                                     boutp + i * H, lnw + i * H, lnb + i * H);
    }
    fc1m_kernel<<<dim3(42, 16), 256, 0, stream>>>(hb2, wcfrag, partial);
    fc1red_kernel<<<768, 256, 0, stream>>>(partial, cbias, t1);
    fc2_kernel<<<768, 256, 0, stream>>>(t1, fc2W, fc2b, (float*)d_out);
}

// Round 8
// 842.153 us; speedup vs baseline: 2.2484x; 1.0400x over previous
//
#include <hip/hip_runtime.h>
#include <hip/hip_bf16.h>
#include <math.h>

#define NB 4
#define B  2048
#define L  168
#define DI 9
#define H  96
#define N2 48

#define USTR  196   // conv u row stride (floats): 16 front pad + 168 + 12 (196%32=4 -> b128 conflict-free)
#define ZSTR2 132   // mix/fc1m zs row stride (ushorts): 128 + 4 pad

typedef short short8 __attribute__((ext_vector_type(8)));
typedef float f32x4  __attribute__((ext_vector_type(4)));
typedef unsigned short u16x8 __attribute__((ext_vector_type(8)));
typedef unsigned short u16x4 __attribute__((ext_vector_type(4)));

__device__ __forceinline__ float gelu_f(float x) {
    float x3 = x * x * x;
    float y  = 0.7978845608028654f * (x + 0.044715f * x3);
    float ey = __expf(2.0f * y);
    float t  = 1.0f - 2.0f / (ey + 1.0f);
    return 0.5f * x * (1.0f + t);
}

__device__ __forceinline__ unsigned short bf16_rne(float x) {
    unsigned u = __float_as_uint(x);
    return (unsigned short)((u + 0x7FFFu + ((u >> 16) & 1u)) >> 16);
}
__device__ __forceinline__ float b2f(unsigned short v) {
    return __uint_as_float((unsigned)v << 16);
}

// ---------------- S4D kernel generation: K[i][h][l] ----------------
__global__ void kgen_kernel(const float* __restrict__ log_dt, const float* __restrict__ lar,
                            const float* __restrict__ aim, const float* __restrict__ cre,
                            const float* __restrict__ cim, float* __restrict__ K)
{
    const int ih   = blockIdx.x;
    const int lane = threadIdx.x;
    float ctre = 0.f, ctim = 0.f, pre = 0.f, pim = 0.f, mre = 0.f, mim = 0.f;
    if (lane < N2) {
        float dt  = expf(log_dt[ih]);
        int   idx = ih * N2 + lane;
        float reA = -expf(lar[idx]);
        float imA = aim[idx];
        float dre = dt * reA, dim = dt * imA;
        float er  = expf(dre);
        float sv, cv;
        sincosf(dim, &sv, &cv);
        mre = er * cv; mim = er * sv;
        float nre = mre - 1.0f, nim = mim;
        float den = reA * reA + imA * imA;
        float tre = (nre * reA + nim * imA) / den;
        float tim = (nim * reA - nre * imA) / den;
        float cr = cre[idx], ci = cim[idx];
        ctre = cr * tre - ci * tim;
        ctim = cr * tim + ci * tre;
        pre = 1.0f; pim = 0.0f;
    }
    float* Kr = K + ih * L;
    for (int l = 0; l < L; ++l) {
        float term = ctre * pre - ctim * pim;
        #pragma unroll
        for (int off = 32; off > 0; off >>= 1) term += __shfl_xor(term, off, 64);
        if (lane == 0) Kr[l] = 2.0f * term;
        float nr = pre * mre - pim * mim;
        float ni = pre * mim + pim * mre;
        pre = nr; pim = ni;
    }
}

// ---------------- prepack W (layers of 96x96, row=k, col=out) into MFMA A-frags hi/lo ----------------
__global__ void wprep_kernel(const float* __restrict__ wout, short* __restrict__ wfrag, int ntask)
{
    int idx = blockIdx.x * 256 + threadIdx.x;
    if (idx >= ntask) return;
    int layer = idx / 9216;  int rem  = idx - layer * 9216;
    int ch    = rem / 3072;  int rem2 = rem - ch * 3072;
    int m     = rem2 / 512;  int rem3 = rem2 - m * 512;
    int s     = rem3 / 256;  int rem4 = rem3 - s * 256;
    int lane  = rem4 / 4;    int d    = rem4 - lane * 4;
    int g = lane >> 4, c = lane & 15;
    int k  = ch * 32 + g * 8 + 2 * d;
    int hp = m * 16 + c;
    const float* Wl = wout + (size_t)layer * H * H;
    float w0 = Wl[k * H + hp];
    float w1 = Wl[(k + 1) * H + hp];
    unsigned short b0, b1;
    if (s == 0) { b0 = bf16_rne(w0); b1 = bf16_rne(w1); }
    else {
        unsigned short h0 = bf16_rne(w0), h1 = bf16_rne(w1);
        b0 = bf16_rne(w0 - b2f(h0));
        b1 = bf16_rne(w1 - b2f(h1));
    }
    wfrag[idx * 2]     = (short)b0;
    wfrag[idx * 2 + 1] = (short)b1;
}

// ---------------- compose decW into fc1W: Wcomp[l*96+k][p] = sum_h decW[k][h]*fc1W[l*96+h][p] ----------------
__launch_bounds__(256)
__global__ void wcomp_kernel(const float* __restrict__ decW, const float* __restrict__ decb,
                             const float* __restrict__ fc1W, float* __restrict__ wcs,
                             float* __restrict__ cbpart)
{
    __shared__ float Bs[96 * 100];
    const int tid = threadIdx.x;
    const int l   = blockIdx.x;
    for (int e = tid; e < 96 * 96; e += 256) {
        int h = e / 96, p = e - h * 96;
        Bs[h * 100 + p] = fc1W[(size_t)(l * 96 + h) * 96 + p];
    }
    __syncthreads();
    const int pt = tid & 31;
    const int kt = tid >> 5;        // 0..7
    float acc[12][3];
    #pragma unroll
    for (int kk = 0; kk < 12; ++kk)
        #pragma unroll
        for (int j = 0; j < 3; ++j) acc[kk][j] = 0.f;
    for (int h = 0; h < 96; ++h) {
        float dw[12];
        #pragma unroll
        for (int kk = 0; kk < 12; ++kk) dw[kk] = decW[(kt + 8 * kk) * 96 + h];
        float bs[3];
        #pragma unroll
        for (int j = 0; j < 3; ++j) bs[j] = Bs[h * 100 + pt + 32 * j];
        #pragma unroll
        for (int kk = 0; kk < 12; ++kk)
            #pragma unroll
            for (int j = 0; j < 3; ++j) acc[kk][j] = fmaf(dw[kk], bs[j], acc[kk][j]);
    }
    float* wl = wcs + (size_t)l * 9216;
    #pragma unroll
    for (int kk = 0; kk < 12; ++kk)
        #pragma unroll
        for (int j = 0; j < 3; ++j)
            wl[(kt + 8 * kk) * 96 + pt + 32 * j] = acc[kk][j];
    if (kt == 0) {
        #pragma unroll
        for (int j = 0; j < 3; ++j) {
            float s = 0.f;
            for (int h = 0; h < 96; ++h) s = fmaf(decb[h], Bs[h * 100 + pt + 32 * j], s);
            cbpart[l * 96 + pt + 32 * j] = s;
        }
    }
}

__global__ void cbias_red_kernel(const float* __restrict__ cbpart, const float* __restrict__ fc1b,
                                 float* __restrict__ cbias)
{
    int p = threadIdx.x;
    if (p < 96) {
        float s = fc1b[p];
        for (int l = 0; l < L; ++l) s += cbpart[l * 96 + p];
        cbias[p] = s;
    }
}

// ---------------- encoder into (h,l,b) bf16 ----------------
__launch_bounds__(256)
__global__ void enc2_kernel(const float* __restrict__ x, const float* __restrict__ W,
                            const float* __restrict__ bias, unsigned short* __restrict__ hb2)
{
    __shared__ float Ws[DI * H];
    __shared__ float bs[H];
    const int tid = threadIdx.x;
    const int l   = blockIdx.x;
    const int b0  = blockIdx.y * 256;
    for (int e = tid; e < DI * H; e += 256) Ws[e] = W[e];
    if (tid < H) bs[tid] = bias[tid];
    __syncthreads();
    float xv[DI];
    const float* xr = x + (size_t)(b0 + tid) * (L * DI) + l * DI;
    #pragma unroll
    for (int k = 0; k < DI; ++k) xv[k] = xr[k];
    for (int h = 0; h < H; ++h) {
        float a = bs[h];
        #pragma unroll
        for (int k = 0; k < DI; ++k) a = fmaf(xv[k], Ws[k * H + h], a);
        hb2[((size_t)h * L + l) * B + b0 + tid] = bf16_rne(a);
    }
}

// ---------------- conv (depthwise causal) + skip + GELU: fp32 VALU, bf16 in/out ----------------
// Staging: global scalar u16 -> regs -> row-local ds_write_b128 (lane=row, stride 196 dw
// == 4 mod 32 banks -> 8-lane phases cover all 32 banks -> conflict-free, like the reads).
__launch_bounds__(256)
__global__ void conv2_kernel(const unsigned short* __restrict__ hb2, const float* __restrict__ Kg,
                             const float* __restrict__ Dsk, unsigned short* __restrict__ z2)
{
    __shared__ __align__(16) float us[64 * USTR];
    __shared__ __align__(16) float Ks[176];
    const int tid = threadIdx.x;
    const int c   = tid >> 6;
    const int bb  = tid & 63;
    const int h   = blockIdx.x;
    const int b0  = blockIdx.y * 64;
    const unsigned short* ub = hb2 + (size_t)h * L * B + b0 + bb;
    float* ur_w = us + bb * USTR;

    // zero pads via row-local b128 (front dwords 0..15, tail 184..195), partitioned by wave
    {
        float4 zz = make_float4(0.f, 0.f, 0.f, 0.f);
        if (c == 0)      { *(float4*)(ur_w + 0)   = zz; *(float4*)(ur_w + 4)   = zz; }
        else if (c == 1) { *(float4*)(ur_w + 8)   = zz; *(float4*)(ur_w + 12)  = zz; }
        else if (c == 2) { *(float4*)(ur_w + 184) = zz; *(float4*)(ur_w + 188) = zz; }
        else             { *(float4*)(ur_w + 192) = zz; }
    }
    // stage u: thread owns row bb, l-groups lg = c, c+4, ... (8 l's each)
    for (int lg = c; lg < 21; lg += 4) {
        float v[8];
        #pragma unroll
        for (int j = 0; j < 8; ++j)
            v[j] = b2f(ub[(size_t)(lg * 8 + j) * B]);
        *(float4*)(ur_w + 16 + lg * 8)     = make_float4(v[0], v[1], v[2], v[3]);
        *(float4*)(ur_w + 16 + lg * 8 + 4) = make_float4(v[4], v[5], v[6], v[7]);
    }
    if (tid < 176) Ks[tid] = (tid < L) ? Kg[h * L + tid] : 0.0f;
    __syncthreads();

    const float ds = Dsk[h];
    const float* ur = us + bb * USTR;
    unsigned short* zb = z2 + (size_t)h * L * B + b0 + bb;
    const int cmap[11] = {2, 3, 3, 3, 0, 1, 2, 3, 2, 1, 0};

    #pragma unroll
    for (int lt = 0; lt < 11; ++lt) {
        if (cmap[lt] != c) continue;
        const int l0 = lt * 16;
        float acc[16];
        #pragma unroll
        for (int i = 0; i < 16; ++i) acc[i] = 0.f;
        for (int d0 = 0; d0 <= l0 + 8; d0 += 8) {
            float4 K0 = *(const float4*)(Ks + d0);
            float4 K1 = *(const float4*)(Ks + d0 + 4);
            float kv[8] = {K0.x, K0.y, K0.z, K0.w, K1.x, K1.y, K1.z, K1.w};
            const float* up = ur + (8 + l0 - d0);
            float4 A0 = *(const float4*)(up);
            float4 A1 = *(const float4*)(up + 4);
            float4 A2 = *(const float4*)(up + 8);
            float4 A3 = *(const float4*)(up + 12);
            float4 A4 = *(const float4*)(up + 16);
            float4 A5 = *(const float4*)(up + 20);
            float uv[24] = {A0.x, A0.y, A0.z, A0.w, A1.x, A1.y, A1.z, A1.w,
                            A2.x, A2.y, A2.z, A2.w, A3.x, A3.y, A3.z, A3.w,
                            A4.x, A4.y, A4.z, A4.w, A5.x, A5.y, A5.z, A5.w};
            #pragma unroll
            for (int dd = 0; dd < 8; ++dd)
                #pragma unroll
                for (int i = 0; i < 16; ++i)
                    acc[i] = fmaf(kv[dd], uv[8 + i - dd], acc[i]);
        }
        #pragma unroll
        for (int i = 0; i < 16; i += 4) {
            float4 U = *(const float4*)(ur + 16 + l0 + i);
            float uu[4] = {U.x, U.y, U.z, U.w};
            #pragma unroll
            for (int r = 0; r < 4; ++r) {
                int l = l0 + i + r;
                if (l < L) {
                    float z = gelu_f(fmaf(ds, uu[r], acc[i + r]));
                    zb[(size_t)l * B] = bf16_rne(z);
                }
            }
        }
    }
}

// ---------------- W_out GEMM (MFMA, W split-2) + bias + residual + LN ----------------
__launch_bounds__(256)
__global__ void mix2_kernel(const unsigned short* __restrict__ z2, unsigned short* __restrict__ hb2,
                            const short* __restrict__ wfrag, const float* __restrict__ bout,
                            const float* __restrict__ lnw, const float* __restrict__ lnb)
{
    __shared__ __align__(16) unsigned short zs[H * ZSTR2];
    const int tid  = threadIdx.x;
    const int w    = tid >> 6;
    const int lane = tid & 63;
    const int g    = lane >> 4;
    const int cc   = lane & 15;
    const int l    = blockIdx.x;
    const int b0   = blockIdx.y * 128;

    for (int e = tid; e < 96 * 16; e += 256) {
        int hh = e >> 4, b8 = e & 15;
        u16x8 v = *(const u16x8*)(z2 + ((size_t)hh * L + l) * B + b0 + b8 * 8);
        *(u16x4*)(&zs[hh * ZSTR2 + b8 * 8])     = (u16x4){v[0], v[1], v[2], v[3]};
        *(u16x4*)(&zs[hh * ZSTR2 + b8 * 8 + 4]) = (u16x4){v[4], v[5], v[6], v[7]};
    }
    __syncthreads();

    f32x4 acc[2][6];
    #pragma unroll
    for (int n2 = 0; n2 < 2; ++n2)
        #pragma unroll
        for (int m = 0; m < 6; ++m) acc[n2][m] = (f32x4){0.f, 0.f, 0.f, 0.f};

    for (int ks = 0; ks < 3; ++ks) {
        short8 bh[2];
        #pragma unroll
        for (int n2 = 0; n2 < 2; ++n2) {
            int col = (w * 2 + n2) * 16 + cc;
            #pragma unroll
            for (int j = 0; j < 8; ++j)
                bh[n2][j] = (short)zs[(ks * 32 + g * 8 + j) * ZSTR2 + col];
        }
        const short8* Wf = (const short8*)(wfrag) + ks * 12 * 64;
        #pragma unroll
        for (int m = 0; m < 6; ++m) {
            short8 ah = Wf[(m * 2 + 0) * 64 + lane];
            short8 al = Wf[(m * 2 + 1) * 64 + lane];
            #pragma unroll
            for (int n2 = 0; n2 < 2; ++n2) {
                acc[n2][m] = __builtin_amdgcn_mfma_f32_16x16x32_bf16(al, bh[n2], acc[n2][m], 0, 0, 0);
                acc[n2][m] = __builtin_amdgcn_mfma_f32_16x16x32_bf16(ah, bh[n2], acc[n2][m], 0, 0, 0);
            }
        }
    }

    #pragma unroll
    for (int n2 = 0; n2 < 2; ++n2) {
        int gb = b0 + (w * 2 + n2) * 16 + cc;
        float vals[6][4];
        float s = 0.f, q = 0.f;
        #pragma unroll
        for (int m = 0; m < 6; ++m) {
            float4 B4 = *(const float4*)(bout + m * 16 + g * 4);
            float bo[4] = {B4.x, B4.y, B4.z, B4.w};
            #pragma unroll
            for (int r = 0; r < 4; ++r) {
                int hr = m * 16 + g * 4 + r;
                float res = b2f(hb2[((size_t)hr * L + l) * B + gb]);
                float v = acc[n2][m][r] + bo[r] + res;
                vals[m][r] = v;
                s += v; q += v * v;
            }
        }
        s += __shfl_xor(s, 16, 64); q += __shfl_xor(q, 16, 64);
        s += __shfl_xor(s, 32, 64); q += __shfl_xor(q, 32, 64);
        float mean = s * (1.0f / 96.0f);
        float var  = q * (1.0f / 96.0f) - mean * mean;
        float rstd = rsqrtf(var + 1e-5f);
        #pragma unroll
        for (int m = 0; m < 6; ++m) {
            float4 W4 = *(const float4*)(lnw + m * 16 + g * 4);
            float4 Bb = *(const float4*)(lnb + m * 16 + g * 4);
            float wv[4] = {W4.x, W4.y, W4.z, W4.w};
            float bv[4] = {Bb.x, Bb.y, Bb.z, Bb.w};
            #pragma unroll
            for (int r = 0; r < 4; ++r) {
                int hr = m * 16 + g * 4 + r;
                hb2[((size_t)hr * L + l) * B + gb] =
                    bf16_rne(fmaf((vals[m][r] - mean) * rstd, wv[r], bv[r]));
            }
        }
    }
}

// ---------------- fc1 via MFMA with composed dec+fc1 weights, split-K over 42 ----------------
__launch_bounds__(256)
__global__ void fc1m_kernel(const unsigned short* __restrict__ hb2, const short* __restrict__ wcfrag,
                            float* __restrict__ partial)
{
    __shared__ __align__(16) unsigned short zs[H * ZSTR2];
    const int tid  = threadIdx.x;
    const int w    = tid >> 6;
    const int lane = tid & 63;
    const int g    = lane >> 4;
    const int cc   = lane & 15;
    const int ksp  = blockIdx.x;       // 0..41 (4 l's each)
    const int b0   = blockIdx.y * 128;

    f32x4 acc[2][6];
    #pragma unroll
    for (int n2 = 0; n2 < 2; ++n2)
        #pragma unroll
        for (int m = 0; m < 6; ++m) acc[n2][m] = (f32x4){0.f, 0.f, 0.f, 0.f};

    for (int il = 0; il < 4; ++il) {
        const int l = ksp * 4 + il;
        __syncthreads();
        for (int e = tid; e < 96 * 16; e += 256) {
            int hh = e >> 4, b8 = e & 15;
            u16x8 v = *(const u16x8*)(hb2 + ((size_t)hh * L + l) * B + b0 + b8 * 8);
            *(u16x4*)(&zs[hh * ZSTR2 + b8 * 8])     = (u16x4){v[0], v[1], v[2], v[3]};
            *(u16x4*)(&zs[hh * ZSTR2 + b8 * 8 + 4]) = (u16x4){v[4], v[5], v[6], v[7]};
        }
        __syncthreads();
        for (int ksl = 0; ksl < 3; ++ksl) {
            short8 bh[2];
            #pragma unroll
            for (int n2 = 0; n2 < 2; ++n2) {
                int col = (w * 2 + n2) * 16 + cc;
                #pragma unroll
                for (int j = 0; j < 8; ++j)
                    bh[n2][j] = (short)zs[(ksl * 32 + g * 8 + j) * ZSTR2 + col];
            }
            const short8* Wf = (const short8*)(wcfrag) + (size_t)(l * 3 + ksl) * 768;
            #pragma unroll
            for (int m = 0; m < 6; ++m) {
                short8 ah = Wf[(m * 2 + 0) * 64 + lane];
                short8 al = Wf[(m * 2 + 1) * 64 + lane];
                #pragma unroll
                for (int n2 = 0; n2 < 2; ++n2) {
                    acc[n2][m] = __builtin_amdgcn_mfma_f32_16x16x32_bf16(al, bh[n2], acc[n2][m], 0, 0, 0);
                    acc[n2][m] = __builtin_amdgcn_mfma_f32_16x16x32_bf16(ah, bh[n2], acc[n2][m], 0, 0, 0);
                }
            }
        }
    }

    #pragma unroll
    for (int n2 = 0; n2 < 2; ++n2) {
        int gb = b0 + (w * 2 + n2) * 16 + cc;
        #pragma unroll
        for (int m = 0; m < 6; ++m) {
            *(float4*)&partial[((size_t)ksp * B + gb) * 96 + m * 16 + g * 4] =
                make_float4(acc[n2][m][0], acc[n2][m][1], acc[n2][m][2], acc[n2][m][3]);
        }
    }
}

__global__ void fc1red_kernel(const float* __restrict__ partial, const float* __restrict__ cbias,
                              float* __restrict__ t1)
{
    int o = blockIdx.x * 256 + threadIdx.x;
    int p = o % 96;
    float s = cbias[p];
    #pragma unroll 6
    for (int k = 0; k < 42; ++k) s += partial[(size_t)k * (B * 96) + o];
    t1[o] = s;
}

__launch_bounds__(256)
__global__ void fc2_kernel(const float* __restrict__ t1, const float* __restrict__ W,
                           const float* __restrict__ fb, float* __restrict__ out)
{
    __shared__ float Ws[96 * 100];
    const int tid = threadIdx.x;
    for (int e = tid; e < 96 * 96; e += 256) Ws[(e / 96) * 100 + (e % 96)] = W[e];
    __syncthreads();
    int o = blockIdx.x * 256 + tid;
    int b = o / 96, p = o - b * 96;
    const float* tr = t1 + b * 96;
    float acc = fb[p];
    #pragma unroll 4
    for (int h = 0; h < 96; ++h) acc = fmaf(tr[h], Ws[h * 100 + p], acc);
    out[o] = acc;
}

extern "C" void kernel_launch(void* const* d_in, const int* in_sizes, int n_in,
                              void* d_out, int out_size, void* d_ws, size_t ws_size,
                              hipStream_t stream)
{
    const float* x      = (const float*)d_in[0];
    const float* encW   = (const float*)d_in[1];
    const float* encb   = (const float*)d_in[2];
    const float* log_dt = (const float*)d_in[3];
    const float* lar    = (const float*)d_in[4];
    const float* aim    = (const float*)d_in[5];
    const float* cre    = (const float*)d_in[6];
    const float* cim    = (const float*)d_in[7];
    const float* dsk    = (const float*)d_in[8];
    const float* wout   = (const float*)d_in[9];
    const float* boutp  = (const float*)d_in[10];
    const float* lnw    = (const float*)d_in[11];
    const float* lnb    = (const float*)d_in[12];
    const float* decW   = (const float*)d_in[13];
    const float* decb   = (const float*)d_in[14];
    const float* fc1W   = (const float*)d_in[15];
    const float* fc1b   = (const float*)d_in[16];
    const float* fc2W   = (const float*)d_in[17];
    const float* fc2b   = (const float*)d_in[18];

    // ws layout (max end ≈ 143 MiB, the round-6-proven envelope):
    char*           ws      = (char*)d_ws;
    float*          K       = (float*)(ws);                          // 258 KB
    short*          wfrag   = (short*)(ws + ((size_t)512 << 10));    // 147 KB (4 wout layers)
    float*          wcs     = (float*)(ws + ((size_t)1 << 20));      // 6.19 MB Wcomp fp32
    short*          wcfrag  = (short*)(ws + ((size_t)7 << 20));      // 6.19 MB Wcomp frags
    float*          cbpart  = (float*)(ws + ((size_t)13 << 20));     // 64.5 KB
    float*          cbias   = (float*)(ws + ((size_t)13 << 20) + (1 << 18)); // 384 B
    float*          t1      = (float*)(ws + ((size_t)14 << 20));     // 786 KB
    unsigned short* hb2     = (unsigned short*)(ws + ((size_t)16 << 20)); // 63 MiB bf16 (h,l,b)
    unsigned short* z2      = (unsigned short*)(ws + ((size_t)80 << 20)); // 63 MiB bf16 (h,l,b)
    float*          partial = (float*)(ws + ((size_t)80 << 20));     // 31.5 MiB, aliases z2 (dead by fc1)

    kgen_kernel<<<NB * H, 64, 0, stream>>>(log_dt, lar, aim, cre, cim, K);
    wprep_kernel<<<144, 256, 0, stream>>>(wout, wfrag, NB * 9216);
    wcomp_kernel<<<L, 256, 0, stream>>>(decW, decb, fc1W, wcs, cbpart);
    wprep_kernel<<<6048, 256, 0, stream>>>(wcs, wcfrag, L * 9216);
    cbias_red_kernel<<<1, 128, 0, stream>>>(cbpart, fc1b, cbias);
    enc2_kernel<<<dim3(L, 8), 256, 0, stream>>>(x, encW, encb, hb2);
    for (int i = 0; i < NB; ++i) {
        conv2_kernel<<<dim3(H, 32), 256, 0, stream>>>(hb2, K + i * H * L, dsk + i * H, z2);
        mix2_kernel<<<dim3(L, 16), 256, 0, stream>>>(z2, hb2, wfrag + i * 18432,
                                                     boutp + i * H, lnw + i * H, lnb + i * H);
    }
    fc1m_kernel<<<dim3(42, 16), 256, 0, stream>>>(hb2, wcfrag, partial);
    fc1red_kernel<<<768, 256, 0, stream>>>(partial, cbias, t1);
    fc2_kernel<<<768, 256, 0, stream>>>(t1, fc2W, fc2b, (float*)d_out);
}

// Round 9
// 637.039 us; speedup vs baseline: 2.9724x; 1.3220x over previous
//
#include <hip/hip_runtime.h>
#include <hip/hip_bf16.h>
#include <math.h>

#define NB 4
#define B  2048
#define L  168
#define DI 9
#define H  96
#define N2 48

#define ZSTR2 132   // zs row stride (ushorts): 128 + 4 pad

typedef short short8 __attribute__((ext_vector_type(8)));
typedef float f32x4  __attribute__((ext_vector_type(4)));
typedef unsigned short u16x8 __attribute__((ext_vector_type(8)));
typedef unsigned short u16x4 __attribute__((ext_vector_type(4)));

__device__ __forceinline__ float gelu_f(float x) {
    float x3 = x * x * x;
    float y  = 0.7978845608028654f * (x + 0.044715f * x3);
    float ey = __expf(2.0f * y);
    float t  = 1.0f - 2.0f / (ey + 1.0f);
    return 0.5f * x * (1.0f + t);
}

__device__ __forceinline__ unsigned short bf16_rne(float x) {
    unsigned u = __float_as_uint(x);
    return (unsigned short)((u + 0x7FFFu + ((u >> 16) & 1u)) >> 16);
}
__device__ __forceinline__ float b2f(unsigned short v) {
    return __uint_as_float((unsigned)v << 16);
}

// ---------------- S4D kernel generation: K[i][h][l] ----------------
__global__ void kgen_kernel(const float* __restrict__ log_dt, const float* __restrict__ lar,
                            const float* __restrict__ aim, const float* __restrict__ cre,
                            const float* __restrict__ cim, float* __restrict__ K)
{
    const int ih   = blockIdx.x;
    const int lane = threadIdx.x;
    float ctre = 0.f, ctim = 0.f, pre = 0.f, pim = 0.f, mre = 0.f, mim = 0.f;
    if (lane < N2) {
        float dt  = expf(log_dt[ih]);
        int   idx = ih * N2 + lane;
        float reA = -expf(lar[idx]);
        float imA = aim[idx];
        float dre = dt * reA, dim = dt * imA;
        float er  = expf(dre);
        float sv, cv;
        sincosf(dim, &sv, &cv);
        mre = er * cv; mim = er * sv;
        float nre = mre - 1.0f, nim = mim;
        float den = reA * reA + imA * imA;
        float tre = (nre * reA + nim * imA) / den;
        float tim = (nim * reA - nre * imA) / den;
        float cr = cre[idx], ci = cim[idx];
        ctre = cr * tre - ci * tim;
        ctim = cr * tim + ci * tre;
        pre = 1.0f; pim = 0.0f;
    }
    float* Kr = K + ih * L;
    for (int l = 0; l < L; ++l) {
        float term = ctre * pre - ctim * pim;
        #pragma unroll
        for (int off = 32; off > 0; off >>= 1) term += __shfl_xor(term, off, 64);
        if (lane == 0) Kr[l] = 2.0f * term;
        float nr = pre * mre - pim * mim;
        float ni = pre * mim + pim * mre;
        pre = nr; pim = ni;
    }
}

// ---------------- prepack W (layers of 96x96, row=k, col=out) into MFMA A-frags hi/lo ----------------
__global__ void wprep_kernel(const float* __restrict__ wout, short* __restrict__ wfrag, int ntask)
{
    int idx = blockIdx.x * 256 + threadIdx.x;
    if (idx >= ntask) return;
    int layer = idx / 9216;  int rem  = idx - layer * 9216;
    int ch    = rem / 3072;  int rem2 = rem - ch * 3072;
    int m     = rem2 / 512;  int rem3 = rem2 - m * 512;
    int s     = rem3 / 256;  int rem4 = rem3 - s * 256;
    int lane  = rem4 / 4;    int d    = rem4 - lane * 4;
    int g = lane >> 4, c = lane & 15;
    int k  = ch * 32 + g * 8 + 2 * d;
    int hp = m * 16 + c;
    const float* Wl = wout + (size_t)layer * H * H;
    float w0 = Wl[k * H + hp];
    float w1 = Wl[(k + 1) * H + hp];
    unsigned short b0, b1;
    if (s == 0) { b0 = bf16_rne(w0); b1 = bf16_rne(w1); }
    else {
        unsigned short h0 = bf16_rne(w0), h1 = bf16_rne(w1);
        b0 = bf16_rne(w0 - b2f(h0));
        b1 = bf16_rne(w1 - b2f(h1));
    }
    wfrag[idx * 2]     = (short)b0;
    wfrag[idx * 2 + 1] = (short)b1;
}

// ---------------- Toeplitz A-fragments for conv: T[l][l'] = K[l-l'] (triangular tiles) ----------------
__global__ void tgen_kernel(const float* __restrict__ Kg, short* __restrict__ tfrag)
{
    static const int kmaxA[11] = {0, 0, 1, 1, 2, 2, 3, 3, 4, 4, 5};
    static const int toffA[11] = {0, 1, 2, 4, 6, 9, 12, 16, 20, 25, 30};
    int idx = blockIdx.x * 256 + threadIdx.x;          // 96*66*64 tasks
    if (idx >= 96 * 66 * 64) return;
    int lane = idx & 63;
    int t    = (idx >> 6) % 66;
    int h    = (idx >> 6) / 66;
    int mi = t / 6, ki = t - mi * 6;
    if (ki > kmaxA[mi]) return;
    int g = lane >> 4, c = lane & 15;
    int row = mi * 16 + c;
    short hi8[8], lo8[8];
    #pragma unroll
    for (int j = 0; j < 8; ++j) {
        int kk = ki * 32 + g * 8 + j;
        int d  = row - kk;
        float val = (row < L && d >= 0) ? Kg[h * L + d] : 0.0f;
        unsigned short hv = bf16_rne(val);
        hi8[j] = (short)hv;
        lo8[j] = (short)bf16_rne(val - b2f(hv));
    }
    short8* dst = (short8*)tfrag + (size_t)((h * 36 + toffA[mi] + ki) * 2) * 64;
    short8 a, b;
    #pragma unroll
    for (int j = 0; j < 8; ++j) { a[j] = hi8[j]; b[j] = lo8[j]; }
    dst[lane]      = a;
    dst[64 + lane] = b;
}

// ---------------- compose decW into fc1W: Wcomp[l*96+k][p] = sum_h decW[k][h]*fc1W[l*96+h][p] ----------------
__launch_bounds__(256)
__global__ void wcomp_kernel(const float* __restrict__ decW, const float* __restrict__ decb,
                             const float* __restrict__ fc1W, float* __restrict__ wcs,
                             float* __restrict__ cbpart)
{
    __shared__ float Bs[96 * 100];
    const int tid = threadIdx.x;
    const int l   = blockIdx.x;
    for (int e = tid; e < 96 * 96; e += 256) {
        int h = e / 96, p = e - h * 96;
        Bs[h * 100 + p] = fc1W[(size_t)(l * 96 + h) * 96 + p];
    }
    __syncthreads();
    const int pt = tid & 31;
    const int kt = tid >> 5;
    float acc[12][3];
    #pragma unroll
    for (int kk = 0; kk < 12; ++kk)
        #pragma unroll
        for (int j = 0; j < 3; ++j) acc[kk][j] = 0.f;
    for (int h = 0; h < 96; ++h) {
        float dw[12];
        #pragma unroll
        for (int kk = 0; kk < 12; ++kk) dw[kk] = decW[(kt + 8 * kk) * 96 + h];
        float bs[3];
        #pragma unroll
        for (int j = 0; j < 3; ++j) bs[j] = Bs[h * 100 + pt + 32 * j];
        #pragma unroll
        for (int kk = 0; kk < 12; ++kk)
            #pragma unroll
            for (int j = 0; j < 3; ++j) acc[kk][j] = fmaf(dw[kk], bs[j], acc[kk][j]);
    }
    float* wl = wcs + (size_t)l * 9216;
    #pragma unroll
    for (int kk = 0; kk < 12; ++kk)
        #pragma unroll
        for (int j = 0; j < 3; ++j)
            wl[(kt + 8 * kk) * 96 + pt + 32 * j] = acc[kk][j];
    if (kt == 0) {
        #pragma unroll
        for (int j = 0; j < 3; ++j) {
            float s = 0.f;
            for (int h = 0; h < 96; ++h) s = fmaf(decb[h], Bs[h * 100 + pt + 32 * j], s);
            cbpart[l * 96 + pt + 32 * j] = s;
        }
    }
}

__global__ void cbias_red_kernel(const float* __restrict__ cbpart, const float* __restrict__ fc1b,
                                 float* __restrict__ cbias)
{
    int p = threadIdx.x;
    if (p < 96) {
        float s = fc1b[p];
        for (int l = 0; l < L; ++l) s += cbpart[l * 96 + p];
        cbias[p] = s;
    }
}

// ---------------- encoder into (h,l,b) bf16 ----------------
__launch_bounds__(256)
__global__ void enc2_kernel(const float* __restrict__ x, const float* __restrict__ W,
                            const float* __restrict__ bias, unsigned short* __restrict__ hb2)
{
    __shared__ float Ws[DI * H];
    __shared__ float bs[H];
    const int tid = threadIdx.x;
    const int l   = blockIdx.x;
    const int b0  = blockIdx.y * 256;
    for (int e = tid; e < DI * H; e += 256) Ws[e] = W[e];
    if (tid < H) bs[tid] = bias[tid];
    __syncthreads();
    float xv[DI];
    const float* xr = x + (size_t)(b0 + tid) * (L * DI) + l * DI;
    #pragma unroll
    for (int k = 0; k < DI; ++k) xv[k] = xr[k];
    for (int h = 0; h < H; ++h) {
        float a = bs[h];
        #pragma unroll
        for (int k = 0; k < DI; ++k) a = fmaf(xv[k], Ws[k * H + h], a);
        hb2[((size_t)h * L + l) * B + b0 + tid] = bf16_rne(a);
    }
}

// ---------------- conv via Toeplitz MFMA + skip + GELU ----------------
__launch_bounds__(256)
__global__ void conv3_kernel(const unsigned short* __restrict__ hb2, const short* __restrict__ tfrag,
                             const float* __restrict__ Dsk, unsigned short* __restrict__ z2)
{
    static const int toffA[11] = {0, 1, 2, 4, 6, 9, 12, 16, 20, 25, 30};
    __shared__ __align__(16) unsigned short zs[192 * ZSTR2];
    const int tid  = threadIdx.x;
    const int w    = tid >> 6;
    const int lane = tid & 63;
    const int g    = lane >> 4;
    const int cc   = lane & 15;
    const int h    = blockIdx.x;
    const int b0   = blockIdx.y * 128;

    // stage u rows 0..167 (bf16), zero rows 168..191
    for (int e = tid; e < 168 * 16; e += 256) {
        int lp = e >> 4, b8 = e & 15;
        u16x8 v = *(const u16x8*)(hb2 + ((size_t)h * L + lp) * B + b0 + b8 * 8);
        *(u16x4*)(&zs[lp * ZSTR2 + b8 * 8])     = (u16x4){v[0], v[1], v[2], v[3]};
        *(u16x4*)(&zs[lp * ZSTR2 + b8 * 8 + 4]) = (u16x4){v[4], v[5], v[6], v[7]};
    }
    for (int e = tid; e < 24 * 16; e += 256) {
        int lp = 168 + (e >> 4), b8 = e & 15;
        *(u16x4*)(&zs[lp * ZSTR2 + b8 * 8])     = (u16x4){0, 0, 0, 0};
        *(u16x4*)(&zs[lp * ZSTR2 + b8 * 8 + 4]) = (u16x4){0, 0, 0, 0};
    }
    __syncthreads();

    f32x4 acc[11][2];
    #pragma unroll
    for (int mi = 0; mi < 11; ++mi) {
        acc[mi][0] = (f32x4){0.f, 0.f, 0.f, 0.f};
        acc[mi][1] = (f32x4){0.f, 0.f, 0.f, 0.f};
    }

    const int col0 = (w * 2 + 0) * 16 + cc;
    const int col1 = (w * 2 + 1) * 16 + cc;

    #pragma unroll
    for (int ki = 0; ki < 6; ++ki) {
        short8 bh0, bh1;
        #pragma unroll
        for (int j = 0; j < 8; ++j) {
            int krow = (ki * 32 + g * 8 + j) * ZSTR2;
            bh0[j] = (short)zs[krow + col0];
            bh1[j] = (short)zs[krow + col1];
        }
        #pragma unroll
        for (int mi = 2 * ki; mi < 11; ++mi) {
            const short8* Tf = (const short8*)(tfrag) + (size_t)((h * 36 + toffA[mi] + ki) * 2) * 64;
            short8 ah = Tf[lane];
            short8 al = Tf[64 + lane];
            acc[mi][0] = __builtin_amdgcn_mfma_f32_16x16x32_bf16(al, bh0, acc[mi][0], 0, 0, 0);
            acc[mi][0] = __builtin_amdgcn_mfma_f32_16x16x32_bf16(ah, bh0, acc[mi][0], 0, 0, 0);
            acc[mi][1] = __builtin_amdgcn_mfma_f32_16x16x32_bf16(al, bh1, acc[mi][1], 0, 0, 0);
            acc[mi][1] = __builtin_amdgcn_mfma_f32_16x16x32_bf16(ah, bh1, acc[mi][1], 0, 0, 0);
        }
    }

    // epilogue: z = gelu(conv + ds*u), store bf16
    const float ds = Dsk[h];
    #pragma unroll
    for (int mi = 0; mi < 11; ++mi) {
        #pragma unroll
        for (int n2 = 0; n2 < 2; ++n2) {
            int col = (w * 2 + n2) * 16 + cc;
            #pragma unroll
            for (int r = 0; r < 4; ++r) {
                int l = mi * 16 + g * 4 + r;
                if (l < L) {
                    float uu = b2f(zs[l * ZSTR2 + col]);
                    float zv = gelu_f(fmaf(ds, uu, acc[mi][n2][r]));
                    z2[((size_t)h * L + l) * B + b0 + col] = bf16_rne(zv);
                }
            }
        }
    }
}

// ---------------- W_out GEMM (MFMA, W split-2) + bias + residual + LN ----------------
__launch_bounds__(256)
__global__ void mix2_kernel(const unsigned short* __restrict__ z2, unsigned short* __restrict__ hb2,
                            const short* __restrict__ wfrag, const float* __restrict__ bout,
                            const float* __restrict__ lnw, const float* __restrict__ lnb)
{
    __shared__ __align__(16) unsigned short zs[H * ZSTR2];
    const int tid  = threadIdx.x;
    const int w    = tid >> 6;
    const int lane = tid & 63;
    const int g    = lane >> 4;
    const int cc   = lane & 15;
    const int l    = blockIdx.x;
    const int b0   = blockIdx.y * 128;

    for (int e = tid; e < 96 * 16; e += 256) {
        int hh = e >> 4, b8 = e & 15;
        u16x8 v = *(const u16x8*)(z2 + ((size_t)hh * L + l) * B + b0 + b8 * 8);
        *(u16x4*)(&zs[hh * ZSTR2 + b8 * 8])     = (u16x4){v[0], v[1], v[2], v[3]};
        *(u16x4*)(&zs[hh * ZSTR2 + b8 * 8 + 4]) = (u16x4){v[4], v[5], v[6], v[7]};
    }
    __syncthreads();

    f32x4 acc[2][6];
    #pragma unroll
    for (int n2 = 0; n2 < 2; ++n2)
        #pragma unroll
        for (int m = 0; m < 6; ++m) acc[n2][m] = (f32x4){0.f, 0.f, 0.f, 0.f};

    for (int ks = 0; ks < 3; ++ks) {
        short8 bh[2];
        #pragma unroll
        for (int n2 = 0; n2 < 2; ++n2) {
            int col = (w * 2 + n2) * 16 + cc;
            #pragma unroll
            for (int j = 0; j < 8; ++j)
                bh[n2][j] = (short)zs[(ks * 32 + g * 8 + j) * ZSTR2 + col];
        }
        const short8* Wf = (const short8*)(wfrag) + ks * 12 * 64;
        #pragma unroll
        for (int m = 0; m < 6; ++m) {
            short8 ah = Wf[(m * 2 + 0) * 64 + lane];
            short8 al = Wf[(m * 2 + 1) * 64 + lane];
            #pragma unroll
            for (int n2 = 0; n2 < 2; ++n2) {
                acc[n2][m] = __builtin_amdgcn_mfma_f32_16x16x32_bf16(al, bh[n2], acc[n2][m], 0, 0, 0);
                acc[n2][m] = __builtin_amdgcn_mfma_f32_16x16x32_bf16(ah, bh[n2], acc[n2][m], 0, 0, 0);
            }
        }
    }

    #pragma unroll
    for (int n2 = 0; n2 < 2; ++n2) {
        int gb = b0 + (w * 2 + n2) * 16 + cc;
        float vals[6][4];
        float s = 0.f, q = 0.f;
        #pragma unroll
        for (int m = 0; m < 6; ++m) {
            float4 B4 = *(const float4*)(bout + m * 16 + g * 4);
            float bo[4] = {B4.x, B4.y, B4.z, B4.w};
            #pragma unroll
            for (int r = 0; r < 4; ++r) {
                int hr = m * 16 + g * 4 + r;
                float res = b2f(hb2[((size_t)hr * L + l) * B + gb]);
                float v = acc[n2][m][r] + bo[r] + res;
                vals[m][r] = v;
                s += v; q += v * v;
            }
        }
        s += __shfl_xor(s, 16, 64); q += __shfl_xor(q, 16, 64);
        s += __shfl_xor(s, 32, 64); q += __shfl_xor(q, 32, 64);
        float mean = s * (1.0f / 96.0f);
        float var  = q * (1.0f / 96.0f) - mean * mean;
        float rstd = rsqrtf(var + 1e-5f);
        #pragma unroll
        for (int m = 0; m < 6; ++m) {
            float4 W4 = *(const float4*)(lnw + m * 16 + g * 4);
            float4 Bb = *(const float4*)(lnb + m * 16 + g * 4);
            float wv[4] = {W4.x, W4.y, W4.z, W4.w};
            float bv[4] = {Bb.x, Bb.y, Bb.z, Bb.w};
            #pragma unroll
            for (int r = 0; r < 4; ++r) {
                int hr = m * 16 + g * 4 + r;
                hb2[((size_t)hr * L + l) * B + gb] =
                    bf16_rne(fmaf((vals[m][r] - mean) * rstd, wv[r], bv[r]));
            }
        }
    }
}

// ---------------- fc1 via MFMA with composed dec+fc1 weights, split-K over 42 ----------------
__launch_bounds__(256)
__global__ void fc1m_kernel(const unsigned short* __restrict__ hb2, const short* __restrict__ wcfrag,
                            float* __restrict__ partial)
{
    __shared__ __align__(16) unsigned short zs[H * ZSTR2];
    const int tid  = threadIdx.x;
    const int w    = tid >> 6;
    const int lane = tid & 63;
    const int g    = lane >> 4;
    const int cc   = lane & 15;
    const int ksp  = blockIdx.x;
    const int b0   = blockIdx.y * 128;

    f32x4 acc[2][6];
    #pragma unroll
    for (int n2 = 0; n2 < 2; ++n2)
        #pragma unroll
        for (int m = 0; m < 6; ++m) acc[n2][m] = (f32x4){0.f, 0.f, 0.f, 0.f};

    for (int il = 0; il < 4; ++il) {
        const int l = ksp * 4 + il;
        __syncthreads();
        for (int e = tid; e < 96 * 16; e += 256) {
            int hh = e >> 4, b8 = e & 15;
            u16x8 v = *(const u16x8*)(hb2 + ((size_t)hh * L + l) * B + b0 + b8 * 8);
            *(u16x4*)(&zs[hh * ZSTR2 + b8 * 8])     = (u16x4){v[0], v[1], v[2], v[3]};
            *(u16x4*)(&zs[hh * ZSTR2 + b8 * 8 + 4]) = (u16x4){v[4], v[5], v[6], v[7]};
        }
        __syncthreads();
        for (int ksl = 0; ksl < 3; ++ksl) {
            short8 bh[2];
            #pragma unroll
            for (int n2 = 0; n2 < 2; ++n2) {
                int col = (w * 2 + n2) * 16 + cc;
                #pragma unroll
                for (int j = 0; j < 8; ++j)
                    bh[n2][j] = (short)zs[(ksl * 32 + g * 8 + j) * ZSTR2 + col];
            }
            const short8* Wf = (const short8*)(wcfrag) + (size_t)(l * 3 + ksl) * 768;
            #pragma unroll
            for (int m = 0; m < 6; ++m) {
                short8 ah = Wf[(m * 2 + 0) * 64 + lane];
                short8 al = Wf[(m * 2 + 1) * 64 + lane];
                #pragma unroll
                for (int n2 = 0; n2 < 2; ++n2) {
                    acc[n2][m] = __builtin_amdgcn_mfma_f32_16x16x32_bf16(al, bh[n2], acc[n2][m], 0, 0, 0);
                    acc[n2][m] = __builtin_amdgcn_mfma_f32_16x16x32_bf16(ah, bh[n2], acc[n2][m], 0, 0, 0);
                }
            }
        }
    }

    #pragma unroll
    for (int n2 = 0; n2 < 2; ++n2) {
        int gb = b0 + (w * 2 + n2) * 16 + cc;
        #pragma unroll
        for (int m = 0; m < 6; ++m) {
            *(float4*)&partial[((size_t)ksp * B + gb) * 96 + m * 16 + g * 4] =
                make_float4(acc[n2][m][0], acc[n2][m][1], acc[n2][m][2], acc[n2][m][3]);
        }
    }
}

__global__ void fc1red_kernel(const float* __restrict__ partial, const float* __restrict__ cbias,
                              float* __restrict__ t1)
{
    int o = blockIdx.x * 256 + threadIdx.x;
    int p = o % 96;
    float s = cbias[p];
    #pragma unroll 6
    for (int k = 0; k < 42; ++k) s += partial[(size_t)k * (B * 96) + o];
    t1[o] = s;
}

__launch_bounds__(256)
__global__ void fc2_kernel(const float* __restrict__ t1, const float* __restrict__ W,
                           const float* __restrict__ fb, float* __restrict__ out)
{
    __shared__ float Ws[96 * 100];
    const int tid = threadIdx.x;
    for (int e = tid; e < 96 * 96; e += 256) Ws[(e / 96) * 100 + (e % 96)] = W[e];
    __syncthreads();
    int o = blockIdx.x * 256 + tid;
    int b = o / 96, p = o - b * 96;
    const float* tr = t1 + b * 96;
    float acc = fb[p];
    #pragma unroll 4
    for (int h = 0; h < 96; ++h) acc = fmaf(tr[h], Ws[h * 100 + p], acc);
    out[o] = acc;
}

extern "C" void kernel_launch(void* const* d_in, const int* in_sizes, int n_in,
                              void* d_out, int out_size, void* d_ws, size_t ws_size,
                              hipStream_t stream)
{
    const float* x      = (const float*)d_in[0];
    const float* encW   = (const float*)d_in[1];
    const float* encb   = (const float*)d_in[2];
    const float* log_dt = (const float*)d_in[3];
    const float* lar    = (const float*)d_in[4];
    const float* aim    = (const float*)d_in[5];
    const float* cre    = (const float*)d_in[6];
    const float* cim    = (const float*)d_in[7];
    const float* dsk    = (const float*)d_in[8];
    const float* wout   = (const float*)d_in[9];
    const float* boutp  = (const float*)d_in[10];
    const float* lnw    = (const float*)d_in[11];
    const float* lnb    = (const float*)d_in[12];
    const float* decW   = (const float*)d_in[13];
    const float* decb   = (const float*)d_in[14];
    const float* fc1W   = (const float*)d_in[15];
    const float* fc1b   = (const float*)d_in[16];
    const float* fc2W   = (const float*)d_in[17];
    const float* fc2b   = (const float*)d_in[18];

    // ws layout (max end = 143 MiB, proven envelope):
    char*           ws      = (char*)d_ws;
    float*          K       = (float*)(ws);                              // 258 KB
    short*          wfrag   = (short*)(ws + ((size_t)384 << 10));        // 147 KB
    float*          t1      = (float*)(ws + ((size_t)1 << 20));          // 786 KB
    float*          cbpart  = (float*)(ws + ((size_t)1 << 20) + (900 << 10)); // 64.5 KB
    float*          cbias   = (float*)(ws + ((size_t)1 << 20) + (980 << 10)); // 384 B
    short*          wcfrag  = (short*)(ws + ((size_t)2 << 20));          // 6.19 MB -> ends 8.2M
    short*          tfrag   = (short*)(ws + ((size_t)9 << 20));          // 6.75 MB -> ends 15.75M
    float*          wcs     = (float*)(ws + ((size_t)9 << 20));          // 6.19 MB, dead before tgen (alias)
    unsigned short* hb2     = (unsigned short*)(ws + ((size_t)16 << 20)); // 63.0 MiB (h,l,b) bf16
    unsigned short* z2      = (unsigned short*)(ws + ((size_t)80 << 20)); // 63.0 MiB (h,l,b) bf16
    float*          partial = (float*)(ws + ((size_t)80 << 20));          // 33 MiB, aliases z2

    kgen_kernel<<<NB * H, 64, 0, stream>>>(log_dt, lar, aim, cre, cim, K);
    wprep_kernel<<<144, 256, 0, stream>>>(wout, wfrag, NB * 9216);
    wcomp_kernel<<<L, 256, 0, stream>>>(decW, decb, fc1W, wcs, cbpart);
    wprep_kernel<<<6048, 256, 0, stream>>>(wcs, wcfrag, L * 9216);
    cbias_red_kernel<<<1, 128, 0, stream>>>(cbpart, fc1b, cbias);
    enc2_kernel<<<dim3(L, 8), 256, 0, stream>>>(x, encW, encb, hb2);
    for (int i = 0; i < NB; ++i) {
        tgen_kernel<<<1584, 256, 0, stream>>>(K + i * H * L, tfrag);
        conv3_kernel<<<dim3(H, 16), 256, 0, stream>>>(hb2, tfrag, dsk + i * H, z2);
        mix2_kernel<<<dim3(L, 16), 256, 0, stream>>>(z2, hb2, wfrag + i * 18432,
                                                     boutp + i * H, lnw + i * H, lnb + i * H);
    }
    fc1m_kernel<<<dim3(42, 16), 256, 0, stream>>>(hb2, wcfrag, partial);
    fc1red_kernel<<<768, 256, 0, stream>>>(partial, cbias, t1);
    fc2_kernel<<<768, 256, 0, stream>>>(t1, fc2W, fc2b, (float*)d_out);
}

// Round 10
// 569.432 us; speedup vs baseline: 3.3253x; 1.1187x over previous
//
#include <hip/hip_runtime.h>
#include <hip/hip_bf16.h>
#include <math.h>

#define NB 4
#define B  2048
#define L  168
#define DI 9
#define H  96
#define N2 48

#define ZSTR2 132   // zs row stride (ushorts): 128 + 4 pad

typedef short short8 __attribute__((ext_vector_type(8)));
typedef float f32x4  __attribute__((ext_vector_type(4)));
typedef unsigned short u16x8 __attribute__((ext_vector_type(8)));
typedef unsigned short u16x4 __attribute__((ext_vector_type(4)));

__device__ __forceinline__ float gelu_f(float x) {
    float x3 = x * x * x;
    float y  = 0.7978845608028654f * (x + 0.044715f * x3);
    float ey = __expf(2.0f * y);
    float t  = 1.0f - 2.0f / (ey + 1.0f);
    return 0.5f * x * (1.0f + t);
}

__device__ __forceinline__ unsigned short bf16_rne(float x) {
    unsigned u = __float_as_uint(x);
    return (unsigned short)((u + 0x7FFFu + ((u >> 16) & 1u)) >> 16);
}
__device__ __forceinline__ float b2f(unsigned short v) {
    return __uint_as_float((unsigned)v << 16);
}

// ---------------- S4D kernel generation: K[i][h][l] ----------------
__global__ void kgen_kernel(const float* __restrict__ log_dt, const float* __restrict__ lar,
                            const float* __restrict__ aim, const float* __restrict__ cre,
                            const float* __restrict__ cim, float* __restrict__ K)
{
    const int ih   = blockIdx.x;
    const int lane = threadIdx.x;
    float ctre = 0.f, ctim = 0.f, pre = 0.f, pim = 0.f, mre = 0.f, mim = 0.f;
    if (lane < N2) {
        float dt  = expf(log_dt[ih]);
        int   idx = ih * N2 + lane;
        float reA = -expf(lar[idx]);
        float imA = aim[idx];
        float dre = dt * reA, dim = dt * imA;
        float er  = expf(dre);
        float sv, cv;
        sincosf(dim, &sv, &cv);
        mre = er * cv; mim = er * sv;
        float nre = mre - 1.0f, nim = mim;
        float den = reA * reA + imA * imA;
        float tre = (nre * reA + nim * imA) / den;
        float tim = (nim * reA - nre * imA) / den;
        float cr = cre[idx], ci = cim[idx];
        ctre = cr * tre - ci * tim;
        ctim = cr * tim + ci * tre;
        pre = 1.0f; pim = 0.0f;
    }
    float* Kr = K + ih * L;
    for (int l = 0; l < L; ++l) {
        float term = ctre * pre - ctim * pim;
        #pragma unroll
        for (int off = 32; off > 0; off >>= 1) term += __shfl_xor(term, off, 64);
        if (lane == 0) Kr[l] = 2.0f * term;
        float nr = pre * mre - pim * mim;
        float ni = pre * mim + pim * mre;
        pre = nr; pim = ni;
    }
}

// ---------------- prepack W (layers of 96x96, row=k, col=out) into MFMA A-frags hi/lo ----------------
__global__ void wprep_kernel(const float* __restrict__ wout, short* __restrict__ wfrag, int ntask)
{
    int idx = blockIdx.x * 256 + threadIdx.x;
    if (idx >= ntask) return;
    int layer = idx / 9216;  int rem  = idx - layer * 9216;
    int ch    = rem / 3072;  int rem2 = rem - ch * 3072;
    int m     = rem2 / 512;  int rem3 = rem2 - m * 512;
    int s     = rem3 / 256;  int rem4 = rem3 - s * 256;
    int lane  = rem4 / 4;    int d    = rem4 - lane * 4;
    int g = lane >> 4, c = lane & 15;
    int k  = ch * 32 + g * 8 + 2 * d;
    int hp = m * 16 + c;
    const float* Wl = wout + (size_t)layer * H * H;
    float w0 = Wl[k * H + hp];
    float w1 = Wl[(k + 1) * H + hp];
    unsigned short b0, b1;
    if (s == 0) { b0 = bf16_rne(w0); b1 = bf16_rne(w1); }
    else {
        unsigned short h0 = bf16_rne(w0), h1 = bf16_rne(w1);
        b0 = bf16_rne(w0 - b2f(h0));
        b1 = bf16_rne(w1 - b2f(h1));
    }
    wfrag[idx * 2]     = (short)b0;
    wfrag[idx * 2 + 1] = (short)b1;
}

// ---------------- Toeplitz A-fragments (hi-only bf16): T[l][l'] = K[l-l'] ----------------
__global__ void tgen_kernel(const float* __restrict__ Kg, short* __restrict__ tfrag)
{
    static const int kmaxA[11] = {0, 0, 1, 1, 2, 2, 3, 3, 4, 4, 5};
    static const int toffA[11] = {0, 1, 2, 4, 6, 9, 12, 16, 20, 25, 30};
    int idx = blockIdx.x * 256 + threadIdx.x;          // 96*66*64 tasks
    if (idx >= 96 * 66 * 64) return;
    int lane = idx & 63;
    int t    = (idx >> 6) % 66;
    int h    = (idx >> 6) / 66;
    int mi = t / 6, ki = t - mi * 6;
    if (ki > kmaxA[mi]) return;
    int g = lane >> 4, c = lane & 15;
    int row = mi * 16 + c;
    short8 a;
    #pragma unroll
    for (int j = 0; j < 8; ++j) {
        int kk = ki * 32 + g * 8 + j;
        int d  = row - kk;
        float val = (row < L && d >= 0) ? Kg[h * L + d] : 0.0f;
        a[j] = (short)bf16_rne(val);
    }
    short8* dst = (short8*)tfrag + (size_t)(h * 36 + toffA[mi] + ki) * 64;
    dst[lane] = a;
}

// ---------------- compose decW into fc1W: Wcomp[l*96+k][p] = sum_h decW[k][h]*fc1W[l*96+h][p] ----------------
__launch_bounds__(256)
__global__ void wcomp_kernel(const float* __restrict__ decW, const float* __restrict__ decb,
                             const float* __restrict__ fc1W, float* __restrict__ wcs,
                             float* __restrict__ cbpart)
{
    __shared__ float Bs[96 * 100];
    const int tid = threadIdx.x;
    const int l   = blockIdx.x;
    for (int e = tid; e < 96 * 96; e += 256) {
        int h = e / 96, p = e - h * 96;
        Bs[h * 100 + p] = fc1W[(size_t)(l * 96 + h) * 96 + p];
    }
    __syncthreads();
    const int pt = tid & 31;
    const int kt = tid >> 5;
    float acc[12][3];
    #pragma unroll
    for (int kk = 0; kk < 12; ++kk)
        #pragma unroll
        for (int j = 0; j < 3; ++j) acc[kk][j] = 0.f;
    for (int h = 0; h < 96; ++h) {
        float dw[12];
        #pragma unroll
        for (int kk = 0; kk < 12; ++kk) dw[kk] = decW[(kt + 8 * kk) * 96 + h];
        float bs[3];
        #pragma unroll
        for (int j = 0; j < 3; ++j) bs[j] = Bs[h * 100 + pt + 32 * j];
        #pragma unroll
        for (int kk = 0; kk < 12; ++kk)
            #pragma unroll
            for (int j = 0; j < 3; ++j) acc[kk][j] = fmaf(dw[kk], bs[j], acc[kk][j]);
    }
    float* wl = wcs + (size_t)l * 9216;
    #pragma unroll
    for (int kk = 0; kk < 12; ++kk)
        #pragma unroll
        for (int j = 0; j < 3; ++j)
            wl[(kt + 8 * kk) * 96 + pt + 32 * j] = acc[kk][j];
    if (kt == 0) {
        #pragma unroll
        for (int j = 0; j < 3; ++j) {
            float s = 0.f;
            for (int h = 0; h < 96; ++h) s = fmaf(decb[h], Bs[h * 100 + pt + 32 * j], s);
            cbpart[l * 96 + pt + 32 * j] = s;
        }
    }
}

__global__ void cbias_red_kernel(const float* __restrict__ cbpart, const float* __restrict__ fc1b,
                                 float* __restrict__ cbias)
{
    int p = threadIdx.x;
    if (p < 96) {
        float s = fc1b[p];
        for (int l = 0; l < L; ++l) s += cbpart[l * 96 + p];
        cbias[p] = s;
    }
}

// ---------------- encoder into (h,l,b) bf16 ----------------
__launch_bounds__(256)
__global__ void enc2_kernel(const float* __restrict__ x, const float* __restrict__ W,
                            const float* __restrict__ bias, unsigned short* __restrict__ hb2)
{
    __shared__ float Ws[DI * H];
    __shared__ float bs[H];
    const int tid = threadIdx.x;
    const int l   = blockIdx.x;
    const int b0  = blockIdx.y * 256;
    for (int e = tid; e < DI * H; e += 256) Ws[e] = W[e];
    if (tid < H) bs[tid] = bias[tid];
    __syncthreads();
    float xv[DI];
    const float* xr = x + (size_t)(b0 + tid) * (L * DI) + l * DI;
    #pragma unroll
    for (int k = 0; k < DI; ++k) xv[k] = xr[k];
    for (int h = 0; h < H; ++h) {
        float a = bs[h];
        #pragma unroll
        for (int k = 0; k < DI; ++k) a = fmaf(xv[k], Ws[k * H + h], a);
        hb2[((size_t)h * L + l) * B + b0 + tid] = bf16_rne(a);
    }
}

// ---------------- conv via Toeplitz MFMA + skip + GELU: 8 waves x 1 n-tile ----------------
__launch_bounds__(512)
__global__ void conv3_kernel(const unsigned short* __restrict__ hb2, const short* __restrict__ tfrag,
                             const float* __restrict__ Dsk, unsigned short* __restrict__ z2)
{
    static const int toffA[11] = {0, 1, 2, 4, 6, 9, 12, 16, 20, 25, 30};
    __shared__ __align__(16) unsigned short zs[192 * ZSTR2];
    const int tid  = threadIdx.x;
    const int w    = tid >> 6;          // 0..7, one 16-col n-tile each
    const int lane = tid & 63;
    const int g    = lane >> 4;
    const int cc   = lane & 15;
    const int h    = blockIdx.x;
    const int b0   = blockIdx.y * 128;

    // stage u rows 0..167 (bf16), zero rows 168..191
    for (int e = tid; e < 168 * 16; e += 512) {
        int lp = e >> 4, b8 = e & 15;
        u16x8 v = *(const u16x8*)(hb2 + ((size_t)h * L + lp) * B + b0 + b8 * 8);
        *(u16x4*)(&zs[lp * ZSTR2 + b8 * 8])     = (u16x4){v[0], v[1], v[2], v[3]};
        *(u16x4*)(&zs[lp * ZSTR2 + b8 * 8 + 4]) = (u16x4){v[4], v[5], v[6], v[7]};
    }
    for (int e = tid; e < 24 * 16; e += 512) {
        int lp = 168 + (e >> 4), b8 = e & 15;
        *(u16x4*)(&zs[lp * ZSTR2 + b8 * 8])     = (u16x4){0, 0, 0, 0};
        *(u16x4*)(&zs[lp * ZSTR2 + b8 * 8 + 4]) = (u16x4){0, 0, 0, 0};
    }
    __syncthreads();

    f32x4 acc[11];
    #pragma unroll
    for (int mi = 0; mi < 11; ++mi) acc[mi] = (f32x4){0.f, 0.f, 0.f, 0.f};

    const int col = w * 16 + cc;

    #pragma unroll
    for (int ki = 0; ki < 6; ++ki) {
        short8 bh;
        #pragma unroll
        for (int j = 0; j < 8; ++j)
            bh[j] = (short)zs[(ki * 32 + g * 8 + j) * ZSTR2 + col];
        #pragma unroll
        for (int mi = 2 * ki; mi < 11; ++mi) {
            const short8* Tf = (const short8*)(tfrag) + (size_t)(h * 36 + toffA[mi] + ki) * 64;
            short8 ah = Tf[lane];
            acc[mi] = __builtin_amdgcn_mfma_f32_16x16x32_bf16(ah, bh, acc[mi], 0, 0, 0);
        }
    }

    // epilogue: z = gelu(conv + ds*u), store bf16
    const float ds = Dsk[h];
    #pragma unroll
    for (int mi = 0; mi < 11; ++mi) {
        #pragma unroll
        for (int r = 0; r < 4; ++r) {
            int l = mi * 16 + g * 4 + r;
            if (l < L) {
                float uu = b2f(zs[l * ZSTR2 + col]);
                float zv = gelu_f(fmaf(ds, uu, acc[mi][r]));
                z2[((size_t)h * L + l) * B + b0 + col] = bf16_rne(zv);
            }
        }
    }
}

// ---------------- W_out GEMM (MFMA, W split-2) + bias + residual + LN ----------------
__launch_bounds__(256)
__global__ void mix2_kernel(const unsigned short* __restrict__ z2, unsigned short* __restrict__ hb2,
                            const short* __restrict__ wfrag, const float* __restrict__ bout,
                            const float* __restrict__ lnw, const float* __restrict__ lnb)
{
    __shared__ __align__(16) unsigned short zs[H * ZSTR2];
    const int tid  = threadIdx.x;
    const int w    = tid >> 6;
    const int lane = tid & 63;
    const int g    = lane >> 4;
    const int cc   = lane & 15;
    const int l    = blockIdx.x;
    const int b0   = blockIdx.y * 128;

    for (int e = tid; e < 96 * 16; e += 256) {
        int hh = e >> 4, b8 = e & 15;
        u16x8 v = *(const u16x8*)(z2 + ((size_t)hh * L + l) * B + b0 + b8 * 8);
        *(u16x4*)(&zs[hh * ZSTR2 + b8 * 8])     = (u16x4){v[0], v[1], v[2], v[3]};
        *(u16x4*)(&zs[hh * ZSTR2 + b8 * 8 + 4]) = (u16x4){v[4], v[5], v[6], v[7]};
    }
    __syncthreads();

    f32x4 acc[2][6];
    #pragma unroll
    for (int n2 = 0; n2 < 2; ++n2)
        #pragma unroll
        for (int m = 0; m < 6; ++m) acc[n2][m] = (f32x4){0.f, 0.f, 0.f, 0.f};

    for (int ks = 0; ks < 3; ++ks) {
        short8 bh[2];
        #pragma unroll
        for (int n2 = 0; n2 < 2; ++n2) {
            int col = (w * 2 + n2) * 16 + cc;
            #pragma unroll
            for (int j = 0; j < 8; ++j)
                bh[n2][j] = (short)zs[(ks * 32 + g * 8 + j) * ZSTR2 + col];
        }
        const short8* Wf = (const short8*)(wfrag) + ks * 12 * 64;
        #pragma unroll
        for (int m = 0; m < 6; ++m) {
            short8 ah = Wf[(m * 2 + 0) * 64 + lane];
            short8 al = Wf[(m * 2 + 1) * 64 + lane];
            #pragma unroll
            for (int n2 = 0; n2 < 2; ++n2) {
                acc[n2][m] = __builtin_amdgcn_mfma_f32_16x16x32_bf16(al, bh[n2], acc[n2][m], 0, 0, 0);
                acc[n2][m] = __builtin_amdgcn_mfma_f32_16x16x32_bf16(ah, bh[n2], acc[n2][m], 0, 0, 0);
            }
        }
    }

    #pragma unroll
    for (int n2 = 0; n2 < 2; ++n2) {
        int gb = b0 + (w * 2 + n2) * 16 + cc;
        float vals[6][4];
        float s = 0.f, q = 0.f;
        #pragma unroll
        for (int m = 0; m < 6; ++m) {
            float4 B4 = *(const float4*)(bout + m * 16 + g * 4);
            float bo[4] = {B4.x, B4.y, B4.z, B4.w};
            #pragma unroll
            for (int r = 0; r < 4; ++r) {
                int hr = m * 16 + g * 4 + r;
                float res = b2f(hb2[((size_t)hr * L + l) * B + gb]);
                float v = acc[n2][m][r] + bo[r] + res;
                vals[m][r] = v;
                s += v; q += v * v;
            }
        }
        s += __shfl_xor(s, 16, 64); q += __shfl_xor(q, 16, 64);
        s += __shfl_xor(s, 32, 64); q += __shfl_xor(q, 32, 64);
        float mean = s * (1.0f / 96.0f);
        float var  = q * (1.0f / 96.0f) - mean * mean;
        float rstd = rsqrtf(var + 1e-5f);
        #pragma unroll
        for (int m = 0; m < 6; ++m) {
            float4 W4 = *(const float4*)(lnw + m * 16 + g * 4);
            float4 Bb = *(const float4*)(lnb + m * 16 + g * 4);
            float wv[4] = {W4.x, W4.y, W4.z, W4.w};
            float bv[4] = {Bb.x, Bb.y, Bb.z, Bb.w};
            #pragma unroll
            for (int r = 0; r < 4; ++r) {
                int hr = m * 16 + g * 4 + r;
                hb2[((size_t)hr * L + l) * B + gb] =
                    bf16_rne(fmaf((vals[m][r] - mean) * rstd, wv[r], bv[r]));
            }
        }
    }
}

// ---------------- fc1 via MFMA with composed dec+fc1 weights, split-K over 42 ----------------
__launch_bounds__(256)
__global__ void fc1m_kernel(const unsigned short* __restrict__ hb2, const short* __restrict__ wcfrag,
                            float* __restrict__ partial)
{
    __shared__ __align__(16) unsigned short zs[H * ZSTR2];
    const int tid  = threadIdx.x;
    const int w    = tid >> 6;
    const int lane = tid & 63;
    const int g    = lane >> 4;
    const int cc   = lane & 15;
    const int ksp  = blockIdx.x;
    const int b0   = blockIdx.y * 128;

    f32x4 acc[2][6];
    #pragma unroll
    for (int n2 = 0; n2 < 2; ++n2)
        #pragma unroll
        for (int m = 0; m < 6; ++m) acc[n2][m] = (f32x4){0.f, 0.f, 0.f, 0.f};

    for (int il = 0; il < 4; ++il) {
        const int l = ksp * 4 + il;
        __syncthreads();
        for (int e = tid; e < 96 * 16; e += 256) {
            int hh = e >> 4, b8 = e & 15;
            u16x8 v = *(const u16x8*)(hb2 + ((size_t)hh * L + l) * B + b0 + b8 * 8);
            *(u16x4*)(&zs[hh * ZSTR2 + b8 * 8])     = (u16x4){v[0], v[1], v[2], v[3]};
            *(u16x4*)(&zs[hh * ZSTR2 + b8 * 8 + 4]) = (u16x4){v[4], v[5], v[6], v[7]};
        }
        __syncthreads();
        for (int ksl = 0; ksl < 3; ++ksl) {
            short8 bh[2];
            #pragma unroll
            for (int n2 = 0; n2 < 2; ++n2) {
                int col = (w * 2 + n2) * 16 + cc;
                #pragma unroll
                for (int j = 0; j < 8; ++j)
                    bh[n2][j] = (short)zs[(ksl * 32 + g * 8 + j) * ZSTR2 + col];
            }
            const short8* Wf = (const short8*)(wcfrag) + (size_t)(l * 3 + ksl) * 768;
            #pragma unroll
            for (int m = 0; m < 6; ++m) {
                short8 ah = Wf[(m * 2 + 0) * 64 + lane];
                short8 al = Wf[(m * 2 + 1) * 64 + lane];
                #pragma unroll
                for (int n2 = 0; n2 < 2; ++n2) {
                    acc[n2][m] = __builtin_amdgcn_mfma_f32_16x16x32_bf16(al, bh[n2], acc[n2][m], 0, 0, 0);
                    acc[n2][m] = __builtin_amdgcn_mfma_f32_16x16x32_bf16(ah, bh[n2], acc[n2][m], 0, 0, 0);
                }
            }
        }
    }

    #pragma unroll
    for (int n2 = 0; n2 < 2; ++n2) {
        int gb = b0 + (w * 2 + n2) * 16 + cc;
        #pragma unroll
        for (int m = 0; m < 6; ++m) {
            *(float4*)&partial[((size_t)ksp * B + gb) * 96 + m * 16 + g * 4] =
                make_float4(acc[n2][m][0], acc[n2][m][1], acc[n2][m][2], acc[n2][m][3]);
        }
    }
}

__global__ void fc1red_kernel(const float* __restrict__ partial, const float* __restrict__ cbias,
                              float* __restrict__ t1)
{
    int o = blockIdx.x * 256 + threadIdx.x;
    int p = o % 96;
    float s = cbias[p];
    #pragma unroll 6
    for (int k = 0; k < 42; ++k) s += partial[(size_t)k * (B * 96) + o];
    t1[o] = s;
}

__launch_bounds__(256)
__global__ void fc2_kernel(const float* __restrict__ t1, const float* __restrict__ W,
                           const float* __restrict__ fb, float* __restrict__ out)
{
    __shared__ float Ws[96 * 100];
    const int tid = threadIdx.x;
    for (int e = tid; e < 96 * 96; e += 256) Ws[(e / 96) * 100 + (e % 96)] = W[e];
    __syncthreads();
    int o = blockIdx.x * 256 + tid;
    int b = o / 96, p = o - b * 96;
    const float* tr = t1 + b * 96;
    float acc = fb[p];
    #pragma unroll 4
    for (int h = 0; h < 96; ++h) acc = fmaf(tr[h], Ws[h * 100 + p], acc);
    out[o] = acc;
}

extern "C" void kernel_launch(void* const* d_in, const int* in_sizes, int n_in,
                              void* d_out, int out_size, void* d_ws, size_t ws_size,
                              hipStream_t stream)
{
    const float* x      = (const float*)d_in[0];
    const float* encW   = (const float*)d_in[1];
    const float* encb   = (const float*)d_in[2];
    const float* log_dt = (const float*)d_in[3];
    const float* lar    = (const float*)d_in[4];
    const float* aim    = (const float*)d_in[5];
    const float* cre    = (const float*)d_in[6];
    const float* cim    = (const float*)d_in[7];
    const float* dsk    = (const float*)d_in[8];
    const float* wout   = (const float*)d_in[9];
    const float* boutp  = (const float*)d_in[10];
    const float* lnw    = (const float*)d_in[11];
    const float* lnb    = (const float*)d_in[12];
    const float* decW   = (const float*)d_in[13];
    const float* decb   = (const float*)d_in[14];
    const float* fc1W   = (const float*)d_in[15];
    const float* fc1b   = (const float*)d_in[16];
    const float* fc2W   = (const float*)d_in[17];
    const float* fc2b   = (const float*)d_in[18];

    // ws layout (max end = 143 MiB, proven envelope):
    char*           ws      = (char*)d_ws;
    float*          K       = (float*)(ws);                              // 258 KB
    short*          wfrag   = (short*)(ws + ((size_t)384 << 10));        // 147 KB
    float*          t1      = (float*)(ws + ((size_t)1 << 20));          // 786 KB
    float*          cbpart  = (float*)(ws + ((size_t)1 << 20) + (900 << 10)); // 64.5 KB
    float*          cbias   = (float*)(ws + ((size_t)1 << 20) + (980 << 10)); // 384 B
    short*          wcfrag  = (short*)(ws + ((size_t)2 << 20));          // 6.19 MB -> ends 8.2M
    short*          tfrag   = (short*)(ws + ((size_t)9 << 20));          // 3.38 MB (hi-only)
    float*          wcs     = (float*)(ws + ((size_t)9 << 20));          // 6.19 MB, dead before tgen (alias)
    unsigned short* hb2     = (unsigned short*)(ws + ((size_t)16 << 20)); // 63.0 MiB (h,l,b) bf16
    unsigned short* z2      = (unsigned short*)(ws + ((size_t)80 << 20)); // 63.0 MiB (h,l,b) bf16
    float*          partial = (float*)(ws + ((size_t)80 << 20));          // 33 MiB, aliases z2

    kgen_kernel<<<NB * H, 64, 0, stream>>>(log_dt, lar, aim, cre, cim, K);
    wprep_kernel<<<144, 256, 0, stream>>>(wout, wfrag, NB * 9216);
    wcomp_kernel<<<L, 256, 0, stream>>>(decW, decb, fc1W, wcs, cbpart);
    wprep_kernel<<<6048, 256, 0, stream>>>(wcs, wcfrag, L * 9216);
    cbias_red_kernel<<<1, 128, 0, stream>>>(cbpart, fc1b, cbias);
    enc2_kernel<<<dim3(L, 8), 256, 0, stream>>>(x, encW, encb, hb2);
    for (int i = 0; i < NB; ++i) {
        tgen_kernel<<<1584, 256, 0, stream>>>(K + i * H * L, tfrag);
        conv3_kernel<<<dim3(H, 16), 512, 0, stream>>>(hb2, tfrag, dsk + i * H, z2);
        mix2_kernel<<<dim3(L, 16), 256, 0, stream>>>(z2, hb2, wfrag + i * 18432,
                                                     boutp + i * H, lnw + i * H, lnb + i * H);
    }
    fc1m_kernel<<<dim3(42, 16), 256, 0, stream>>>(hb2, wcfrag, partial);
    fc1red_kernel<<<768, 256, 0, stream>>>(partial, cbias, t1);
    fc2_kernel<<<768, 256, 0, stream>>>(t1, fc2W, fc2b, (float*)d_out);
}